// Round 16
// baseline (5765.899 us; speedup 1.0000x reference)
//
#include <hip/hip_runtime.h>
#include <hip/hip_fp16.h>
#include <math.h>

#define T_STEPS 128
#define B_SZ 256
#define AD 16
#define ZD 32
#define KM 8
#define HID 128
#define G4H 512

// ws layout (4-byte word offsets)
#define WS_WQ   0
#define WS_WI0  98304
#define WS_BS0  102400
#define WS_BS1  102912
#define WS_Q    103424
#define WS_R    104448

typedef float f32x4 __attribute__((ext_vector_type(4)));

__device__ __forceinline__ unsigned pk16(float lo, float hi) {
  unsigned a = __half_as_ushort(__float2half_rn(lo));
  unsigned b = __half_as_ushort(__float2half_rn(hi));
  return a | (b << 16);
}

__global__ void ssm_prep_kernel(const float* __restrict__ Wih0, const float* __restrict__ Whh0,
                                const float* __restrict__ Wih1, const float* __restrict__ Whh1,
                                const float* __restrict__ bih0, const float* __restrict__ bhh0,
                                const float* __restrict__ bih1, const float* __restrict__ bhh1,
                                const float* __restrict__ QL, const float* __restrict__ RL,
                                float* __restrict__ ws) {
  unsigned* wsu = (unsigned*)ws;
  int tid = blockIdx.x * blockDim.x + threadIdx.x;
  int nt = gridDim.x * blockDim.x;
  for (int j = tid; j < G4H; j += nt) {
    for (int d4 = 0; d4 < 48; ++d4) {
      for (int m = 0; m < 4; ++m) {
        int dd = (d4 & 15) * 4 + m;
        const float* src = (d4 < 16) ? Whh0 : (d4 < 32) ? Wih1 : Whh1;
        wsu[WS_WQ + (d4 * 512 + j) * 4 + m] =
            pk16(src[j * 128 + 2 * dd], src[j * 128 + 2 * dd + 1]);
      }
    }
    for (int k = 0; k < 8; ++k)
      wsu[WS_WI0 + k * 512 + j] = pk16(Wih0[j * 16 + 2 * k], Wih0[j * 16 + 2 * k + 1]);
    ws[WS_BS0 + j] = bih0[j] + bhh0[j];
    ws[WS_BS1 + j] = bih1[j] + bhh1[j];
  }
  for (int e = tid; e < ZD * ZD; e += nt) {
    int i = e >> 5, j = e & 31;
    float s = 0.f;
    for (int k = 0; k < ZD; ++k) s += QL[i * ZD + k] * QL[j * ZD + k];
    if (i == j) s += 0.001f;
    ws[WS_Q + e] = s;
  }
  for (int e = tid; e < AD * AD; e += nt) {
    int i = e >> 4, j = e & 15;
    float s = 0.f;
    for (int k = 0; k < AD; ++k) s += RL[i * AD + k] * RL[j * AD + k];
    if (i == j) s += 0.001f;
    ws[WS_R + e] = s;
  }
}

__device__ __forceinline__ float sigm(float x) { return 1.0f / (1.0f + expf(-x)); }
__device__ __forceinline__ float dotv(f32x4 a, f32x4 b) {
  return a[0] * b[0] + a[1] * b[1] + a[2] * b[2] + a[3] * b[3];
}
__device__ __forceinline__ void st_nt(float* p, float v) { __builtin_nontemporal_store(v, p); }
__device__ __forceinline__ void st_nt4(float* p, f32x4 v) {
  __builtin_nontemporal_store(v, (f32x4*)p);
}

__device__ __forceinline__ float dot2f(unsigned a, unsigned b, float c) {
#if __has_builtin(__builtin_amdgcn_fdot2)
  typedef _Float16 h2 __attribute__((ext_vector_type(2)));
  union U { unsigned u; h2 h; };
  U ua, ub; ua.u = a; ub.u = b;
  return __builtin_amdgcn_fdot2(ua.h, ub.h, c, false);
#else
  union U { unsigned u; _Float16 h[2]; };
  U ua, ub; ua.u = a; ub.u = b;
  return c + (float)ua.h[0] * (float)ub.h[0] + (float)ua.h[1] * (float)ub.h[1];
#endif
}

// Single-block producer/consumer: threads 0..255 Kalman (step i-2), 256..511 LSTM (step i).
// Handoff via 4-deep LDS rings; 8 block-wide barriers per iteration; no atomics/flags.
struct alignas(16) FS {
  // Kalman state
  float P[ZD * 36];
  float Mt[ZD * 36];       // cov_t / M2 (unsym)
  float Sy[ZD * 36];       // sym(cov_t)
  float ACt[ZD * 36];
  float Qs[ZD * 36];
  float Aug[AD * 52];      // [S(16) | CP(32)]
  float Kk[ZD * 20];
  float Rs[AD * AD];
  float meanp[ZD], meant[ZD], r[AD];
  // rings (slot = idx & 3): C_t, A_t, a_t
  float Cring[4][AD * 36];
  float Aring[4][ZD * 36];
  float afr[4][AD];
  // LSTM scratch
  unsigned ap[8];
  unsigned h0p[64];
  unsigned h1p[64];
  float g[G4H];
  float lgp[16];
};

__global__ void __launch_bounds__(512, 2) ssm_fused_kernel(
    const float* __restrict__ as_, const float* __restrict__ AK, const float* __restrict__ CK,
    const float* __restrict__ Wout, const float* __restrict__ bout,
    const float* __restrict__ initm, const float* __restrict__ initc,
    const float* __restrict__ ws, float* __restrict__ out) {
  __shared__ FS s;
  const int tid = threadIdx.x;
  const int b = blockIdx.x;
  const bool isK = (tid < 256);
  const int kl = tid;            // Kalman lane (valid when isK)
  const int lt = tid - 256;      // LSTM lane (valid when !isK)
  const unsigned* wsu = (const unsigned*)ws;

  float* o_means = out;
  float* o_covs = o_means + (size_t)T_STEPS * B_SZ * ZD;
  float* o_nmean = o_covs + (size_t)T_STEPS * B_SZ * ZD * ZD;
  float* o_ncovs = o_nmean + (size_t)T_STEPS * B_SZ * ZD;
  float* o_As = o_ncovs + (size_t)T_STEPS * B_SZ * ZD * ZD;
  float* o_Cs = o_As + (size_t)(T_STEPS + 1) * B_SZ * ZD * ZD;
  float* o_a = o_Cs + (size_t)(T_STEPS + 1) * B_SZ * AD * ZD;

  f32x4* P4 = (f32x4*)s.P;      // stride 9
  f32x4* Mt4 = (f32x4*)s.Mt;
  f32x4* Sy4 = (f32x4*)s.Sy;
  f32x4* ACt4 = (f32x4*)s.ACt;
  f32x4* Q4 = (f32x4*)s.Qs;
  f32x4* Aug4 = (f32x4*)s.Aug;  // stride 13; CP at +4
  f32x4* Kk4 = (f32x4*)s.Kk;    // stride 5
  const f32x4* r4 = (const f32x4*)s.r;
  const f32x4* meanp4 = (const f32x4*)s.meanp;
  const f32x4* meant4 = (const f32x4*)s.meant;
  const uint4* h0p4 = (const uint4*)s.h0p;
  const uint4* h1p4 = (const uint4*)s.h1p;
  const uint4* ap4 = (const uint4*)s.ap;
  const uint4* Wg = (const uint4*)(wsu + WS_WQ);
  const f32x4* AK4 = (const f32x4*)AK;
  const f32x4* CK4 = (const f32x4*)CK;

  const int i32 = kl & 31, cq = (kl & 255) >> 5;   // Kalman 32-row tiles
  const int i16 = kl & 15, j16 = (kl & 255) >> 4;  // Kalman 16-row phases

  // ---- LSTM persistent registers ----
  unsigned wi0rA[8], wi0rB[8];
  float bs0rA = 0.f, bs0rB = 0.f, bs1rA = 0.f, bs1rB = 0.f;
  float woutr[8], boutr[8];
  float c0r = 0.f, c1r = 0.f;
  float ga = 0.f, gb = 0.f;  // cross-segment gate accumulators

  if (!isK) {
    #pragma unroll
    for (int k = 0; k < 8; ++k) {
      wi0rA[k] = wsu[WS_WI0 + k * 512 + lt];
      wi0rB[k] = wsu[WS_WI0 + k * 512 + lt + 256];
    }
    bs0rA = ws[WS_BS0 + lt];
    bs0rB = ws[WS_BS0 + lt + 256];
    bs1rA = ws[WS_BS1 + lt];
    bs1rB = ws[WS_BS1 + lt + 256];
    #pragma unroll
    for (int gi = 0; gi < KM; ++gi) woutr[gi] = (lt < HID) ? Wout[gi * HID + lt] : 0.f;
    #pragma unroll
    for (int k = 0; k < KM; ++k) boutr[k] = bout[k];
    // init: C_0 ring+out, A_0 out, a_0 ring+out, h/c zero
    if (lt < 128) {
      f32x4 acc = {0.f, 0.f, 0.f, 0.f};
      #pragma unroll
      for (int k = 0; k < KM; ++k) acc += CK4[k * 128 + lt];
      ((f32x4*)s.Cring[0])[(lt >> 3) * 9 + (lt & 7)] = acc;
      st_nt4(&o_Cs[(size_t)b * 512 + lt * 4], acc);
    }
    {
      f32x4 acc = {0.f, 0.f, 0.f, 0.f};
      #pragma unroll
      for (int k = 0; k < KM; ++k) acc += AK4[k * 256 + lt];
      st_nt4(&o_As[(size_t)b * 1024 + lt * 4], acc);
    }
    if (lt >= 240) {
      int i2 = lt - 240;
      float v = as_[(size_t)b * AD + i2];
      s.afr[0][i2] = v;
      ((__half*)s.ap)[i2] = __float2half_rn(v);
      st_nt(&o_a[(size_t)b * AD + i2], v);
    }
    if (lt < 64) { s.h0p[lt] = 0u; s.h1p[lt] = 0u; }
  } else {
    #pragma unroll
    for (int q = 0; q < 4; ++q) {
      int e = q * 256 + kl;
      s.P[(e >> 5) * 36 + (e & 31)] = initc[e];
      s.Qs[(e >> 5) * 36 + (e & 31)] = ws[WS_Q + e];
    }
    s.Rs[kl] = ws[WS_R + kl];
    if (kl < ZD) s.meanp[kl] = initm[kl];
  }
  __syncthreads();

  for (int i = 0; i < T_STEPS + 2; ++i) {
    const bool lact = (i < T_STEPS);
    const bool kact = (i >= 2);
    const int t = i - 2;
    const size_t tb = (size_t)(t < 0 ? 0 : t) * B_SZ + b;
    const size_t tb2 = (size_t)(i + 1) * B_SZ + b;
    const f32x4* Cc = (const f32x4*)s.Cring[t & 3];      // C_t
    const f32x4* Ac = (const f32x4*)s.Aring[(t + 1) & 3]; // A_{t+1}

    // ===== seg0: K-P1 (CP = C@P -> Aug right)  |  L-A1 (L0 gates, first half) =====
    if (isK) {
      if (kact) {
        float a0 = 0.f, a1 = 0.f;
        #pragma unroll
        for (int k4 = 0; k4 < 8; ++k4) {
          f32x4 cr = Cc[i16 * 9 + k4];
          a0 += dotv(cr, P4[j16 * 9 + k4]);
          a1 += dotv(cr, P4[(j16 + 16) * 9 + k4]);
        }
        s.Aug[i16 * 52 + AD + j16] = a0;
        s.Aug[i16 * 52 + AD + j16 + 16] = a1;
      }
    } else if (lact) {
      ga = bs0rA;
      gb = bs0rB;
      #pragma unroll
      for (int k4 = 0; k4 < 2; ++k4) {
        uint4 av = ap4[k4];
        ga = dot2f(av.x, wi0rA[k4 * 4 + 0], ga);
        ga = dot2f(av.y, wi0rA[k4 * 4 + 1], ga);
        ga = dot2f(av.z, wi0rA[k4 * 4 + 2], ga);
        ga = dot2f(av.w, wi0rA[k4 * 4 + 3], ga);
        gb = dot2f(av.x, wi0rB[k4 * 4 + 0], gb);
        gb = dot2f(av.y, wi0rB[k4 * 4 + 1], gb);
        gb = dot2f(av.z, wi0rB[k4 * 4 + 2], gb);
        gb = dot2f(av.w, wi0rB[k4 * 4 + 3], gb);
      }
      #pragma unroll
      for (int d4 = 0; d4 < 8; ++d4) {
        uint4 hv = h0p4[d4];
        uint4 wA = Wg[d4 * 512 + lt];
        uint4 wB = Wg[d4 * 512 + lt + 256];
        ga = dot2f(hv.x, wA.x, ga); ga = dot2f(hv.y, wA.y, ga);
        ga = dot2f(hv.z, wA.z, ga); ga = dot2f(hv.w, wA.w, ga);
        gb = dot2f(hv.x, wB.x, gb); gb = dot2f(hv.y, wB.y, gb);
        gb = dot2f(hv.z, wB.z, gb); gb = dot2f(hv.w, wB.w, gb);
      }
    }
    __syncthreads();

    // ===== seg1: K-P2 (S + r)  |  L-A2 (L0 gates, second half; write g) =====
    if (isK) {
      if (kact) {
        float b0 = s.Rs[i16 * AD + j16];
        #pragma unroll
        for (int k4 = 0; k4 < 8; ++k4)
          b0 += dotv(Aug4[i16 * 13 + 4 + k4], Cc[j16 * 9 + k4]);
        s.Aug[i16 * 52 + j16] = b0;
        if (kl >= 240) {
          int ii = kl - 240;
          float rr = s.afr[t & 3][ii];
          #pragma unroll
          for (int k4 = 0; k4 < 8; ++k4) rr -= dotv(Cc[ii * 9 + k4], meanp4[k4]);
          s.r[ii] = rr;
        }
      }
    } else if (lact) {
      #pragma unroll
      for (int d4 = 8; d4 < 16; ++d4) {
        uint4 hv = h0p4[d4];
        uint4 wA = Wg[d4 * 512 + lt];
        uint4 wB = Wg[d4 * 512 + lt + 256];
        ga = dot2f(hv.x, wA.x, ga); ga = dot2f(hv.y, wA.y, ga);
        ga = dot2f(hv.z, wA.z, ga); ga = dot2f(hv.w, wA.w, ga);
        gb = dot2f(hv.x, wB.x, gb); gb = dot2f(hv.y, wB.y, gb);
        gb = dot2f(hv.z, wB.z, gb); gb = dot2f(hv.w, wB.w, gb);
      }
      s.g[lt] = ga;
      s.g[lt + 256] = gb;
    }
    __syncthreads();

    // ===== seg2: K-P3 (GJ on wave 0)  |  L-B (h0/c0) =====
    if (isK) {
      if (kact && kl < 64) {
        const int lc = (kl < 48) ? kl : 47;
        float col[16];
        #pragma unroll
        for (int q = 0; q < AD; ++q) col[q] = s.Aug[q * 52 + lc];
        #pragma unroll
        for (int j = 0; j < AD; ++j) {
          float pd = __shfl(col[j], j);
          float pinv = 1.0f / pd;
          float oldj = col[j];
          #pragma unroll
          for (int q = 0; q < AD; ++q) {
            if (q == j) continue;
            float fi = __shfl(col[q], j);
            col[q] = fmaf(-(fi * pinv), oldj, col[q]);
          }
          col[j] = oldj * pinv;
        }
        if (kl >= AD && kl < AD + ZD) {
          int rr = kl - AD;
          f32x4 v0 = {col[0], col[1], col[2], col[3]};
          f32x4 v1 = {col[4], col[5], col[6], col[7]};
          f32x4 v2 = {col[8], col[9], col[10], col[11]};
          f32x4 v3 = {col[12], col[13], col[14], col[15]};
          Kk4[rr * 5 + 0] = v0;
          Kk4[rr * 5 + 1] = v1;
          Kk4[rr * 5 + 2] = v2;
          Kk4[rr * 5 + 3] = v3;
        }
      }
    } else if (lact && lt < HID) {
      float ig = sigm(s.g[lt]);
      float fg = sigm(s.g[HID + lt]);
      float gg = tanhf(s.g[2 * HID + lt]);
      float og = sigm(s.g[3 * HID + lt]);
      c0r = fg * c0r + ig * gg;
      ((__half*)s.h0p)[lt] = __float2half_rn(og * tanhf(c0r));
    }
    __syncthreads();

    // ===== seg3: K-P4 (cov_t -> Mt; mean_t)  |  L-C1 (W_ih1 gates) =====
    if (isK) {
      if (kact) {
        if (kl < ZD) {
          float acc = s.meanp[kl];
          #pragma unroll
          for (int m = 0; m < 4; ++m) acc += dotv(Kk4[kl * 5 + m], r4[m]);
          s.meant[kl] = acc;
          st_nt(&o_means[tb * ZD + kl], acc);
        }
        f32x4 acc = {0.f, 0.f, 0.f, 0.f};
        #pragma unroll
        for (int k4 = 0; k4 < 4; ++k4) {
          f32x4 kv = Kk4[i32 * 5 + k4];
          #pragma unroll
          for (int kk = 0; kk < 4; ++kk)
            acc += kv[kk] * Aug4[(4 * k4 + kk) * 13 + 4 + cq];
        }
        Mt4[i32 * 9 + cq] = P4[i32 * 9 + cq] - acc;
      }
    } else if (lact) {
      ga = bs1rA;
      gb = bs1rB;
      #pragma unroll
      for (int d4 = 0; d4 < 16; ++d4) {
        uint4 hv = h0p4[d4];
        uint4 wA = Wg[(16 + d4) * 512 + lt];
        uint4 wB = Wg[(16 + d4) * 512 + lt + 256];
        ga = dot2f(hv.x, wA.x, ga); ga = dot2f(hv.y, wA.y, ga);
        ga = dot2f(hv.z, wA.z, ga); ga = dot2f(hv.w, wA.w, ga);
        gb = dot2f(hv.x, wB.x, gb); gb = dot2f(hv.y, wB.y, gb);
        gb = dot2f(hv.z, wB.z, gb); gb = dot2f(hv.w, wB.w, gb);
      }
    }
    __syncthreads();

    // ===== seg4: K-P5 (Sy + covs out)  |  L-C2 (W_hh1 gates; write g) =====
    if (isK) {
      if (kact) {
        f32x4 mv = Mt4[i32 * 9 + cq];
        f32x4 sv;
        #pragma unroll
        for (int jj = 0; jj < 4; ++jj)
          sv[jj] = 0.5f * (mv[jj] + s.Mt[(4 * cq + jj) * 36 + i32]);
        Sy4[i32 * 9 + cq] = sv;
        st_nt4(&o_covs[tb * 1024 + i32 * 32 + cq * 4], sv);
      }
    } else if (lact) {
      #pragma unroll
      for (int d4 = 0; d4 < 16; ++d4) {
        uint4 hv = h1p4[d4];
        uint4 wA = Wg[(32 + d4) * 512 + lt];
        uint4 wB = Wg[(32 + d4) * 512 + lt + 256];
        ga = dot2f(hv.x, wA.x, ga); ga = dot2f(hv.y, wA.y, ga);
        ga = dot2f(hv.z, wA.z, ga); ga = dot2f(hv.w, wA.w, ga);
        gb = dot2f(hv.x, wB.x, gb); gb = dot2f(hv.y, wB.y, gb);
        gb = dot2f(hv.z, wB.z, gb); gb = dot2f(hv.w, wB.w, gb);
      }
      s.g[lt] = ga;
      s.g[lt + 256] = gb;
    }
    __syncthreads();

    // ===== seg5: K-P6 (ACt = An @ Sy)  |  L-D (h1/c1 + logit partials) =====
    if (isK) {
      if (kact) {
        float c0 = 0.f, c1 = 0.f, c2 = 0.f, c3 = 0.f;
        #pragma unroll
        for (int k4 = 0; k4 < 8; ++k4) {
          f32x4 an = Ac[i32 * 9 + k4];
          c0 += dotv(an, Sy4[(4 * cq + 0) * 9 + k4]);
          c1 += dotv(an, Sy4[(4 * cq + 1) * 9 + k4]);
          c2 += dotv(an, Sy4[(4 * cq + 2) * 9 + k4]);
          c3 += dotv(an, Sy4[(4 * cq + 3) * 9 + k4]);
        }
        f32x4 v = {c0, c1, c2, c3};
        ACt4[i32 * 9 + cq] = v;
      }
    } else if (lact && lt < HID) {
      float ig = sigm(s.g[lt]);
      float fg = sigm(s.g[HID + lt]);
      float gg = tanhf(s.g[2 * HID + lt]);
      float og = sigm(s.g[3 * HID + lt]);
      c1r = fg * c1r + ig * gg;
      float h1u = og * tanhf(c1r);
      ((__half*)s.h1p)[lt] = __float2half_rn(h1u);
      int w2 = lt >> 6, lane = lt & 63;
      #pragma unroll
      for (int gi = 0; gi < KM; ++gi) {
        float p = woutr[gi] * h1u;
        #pragma unroll
        for (int m = 32; m >= 1; m >>= 1) p += __shfl_xor(p, m);
        if (lane == 0) s.lgp[w2 * KM + gi] = p;
      }
    }
    __syncthreads();

    // ===== seg6: K-P7 (M2 -> Mt; meanp')  |  L-E (softmax + rings + outputs) =====
    if (isK) {
      if (kact) {
        if (kl < ZD) {
          float acc = 0.f;
          #pragma unroll
          for (int k4 = 0; k4 < 8; ++k4) acc += dotv(Ac[kl * 9 + k4], meant4[k4]);
          s.meanp[kl] = acc;
          st_nt(&o_nmean[tb * ZD + kl], acc);
        }
        float c0 = 0.f, c1 = 0.f, c2 = 0.f, c3 = 0.f;
        #pragma unroll
        for (int k4 = 0; k4 < 8; ++k4) {
          f32x4 ac = ACt4[i32 * 9 + k4];
          c0 += dotv(ac, Ac[(4 * cq + 0) * 9 + k4]);
          c1 += dotv(ac, Ac[(4 * cq + 1) * 9 + k4]);
          c2 += dotv(ac, Ac[(4 * cq + 2) * 9 + k4]);
          c3 += dotv(ac, Ac[(4 * cq + 3) * 9 + k4]);
        }
        f32x4 mv = {c0, c1, c2, c3};
        Mt4[i32 * 9 + cq] = mv;
      }
    } else if (lact) {
      float lg[KM];
      float mx = -1e30f;
      #pragma unroll
      for (int k = 0; k < KM; ++k) {
        lg[k] = s.lgp[k] + s.lgp[KM + k] + boutr[k];
        mx = fmaxf(mx, lg[k]);
      }
      float sum = 0.f;
      #pragma unroll
      for (int k = 0; k < KM; ++k) { lg[k] = expf(lg[k] - mx); sum += lg[k]; }
      float inv = 1.0f / sum;
      #pragma unroll
      for (int k = 0; k < KM; ++k) lg[k] *= inv;
      {  // A_{i+1}: ring + out
        f32x4 acc = {0.f, 0.f, 0.f, 0.f};
        #pragma unroll
        for (int k = 0; k < KM; ++k) acc += lg[k] * AK4[k * 256 + lt];
        ((f32x4*)s.Aring[(i + 1) & 3])[(lt >> 3) * 9 + (lt & 7)] = acc;
        st_nt4(&o_As[tb2 * 1024 + lt * 4], acc);
      }
      if (lt < 128) {  // C_{i+1}: ring + out
        f32x4 acc = {0.f, 0.f, 0.f, 0.f};
        #pragma unroll
        for (int k = 0; k < KM; ++k) acc += lg[k] * CK4[k * 128 + lt];
        ((f32x4*)s.Cring[(i + 1) & 3])[(lt >> 3) * 9 + (lt & 7)] = acc;
        st_nt4(&o_Cs[tb2 * 512 + lt * 4], acc);
      } else if (lt >= 240 && i + 1 < T_STEPS) {  // a_{i+1}: ring + out + pack
        int i2 = lt - 240;
        float v = as_[tb2 * AD + i2];
        s.afr[(i + 1) & 3][i2] = v;
        ((__half*)s.ap)[i2] = __float2half_rn(v);
        st_nt(&o_a[tb2 * AD + i2], v);
      }
    }
    __syncthreads();

    // ===== seg7: K-P8 (P' = sym(M2)+Q -> P; ncovs out)  |  L-idle =====
    if (isK && kact) {
      f32x4 mv = Mt4[i32 * 9 + cq];
      f32x4 pv;
      #pragma unroll
      for (int jj = 0; jj < 4; ++jj)
        pv[jj] = 0.5f * (mv[jj] + s.Mt[(4 * cq + jj) * 36 + i32]);
      pv += Q4[i32 * 9 + cq];
      P4[i32 * 9 + cq] = pv;
      st_nt4(&o_ncovs[tb * 1024 + i32 * 32 + cq * 4], pv);
    }
    __syncthreads();
  }
}

extern "C" void kernel_launch(void* const* d_in, const int* in_sizes, int n_in,
                              void* d_out, int out_size, void* d_ws, size_t ws_size,
                              hipStream_t stream) {
  const float* as_ = (const float*)d_in[0];
  const float* AK = (const float*)d_in[1];
  const float* CK = (const float*)d_in[2];
  const float* QL = (const float*)d_in[3];
  const float* RL = (const float*)d_in[4];
  const float* initm = (const float*)d_in[5];
  const float* initc = (const float*)d_in[6];
  const float* Wih0 = (const float*)d_in[7];
  const float* Whh0 = (const float*)d_in[8];
  const float* bih0 = (const float*)d_in[9];
  const float* bhh0 = (const float*)d_in[10];
  const float* Wih1 = (const float*)d_in[11];
  const float* Whh1 = (const float*)d_in[12];
  const float* bih1 = (const float*)d_in[13];
  const float* bhh1 = (const float*)d_in[14];
  const float* Wout = (const float*)d_in[15];
  const float* bout = (const float*)d_in[16];
  float* ws = (float*)d_ws;
  float* out = (float*)d_out;

  ssm_prep_kernel<<<16, 256, 0, stream>>>(Wih0, Whh0, Wih1, Whh1, bih0, bhh0, bih1, bhh1,
                                          QL, RL, ws);
  ssm_fused_kernel<<<B_SZ, 512, 0, stream>>>(as_, AK, CK, Wout, bout, initm, initc, ws, out);
}

// Round 17
// 2319.546 us; speedup vs baseline: 2.4858x; 2.4858x over previous
//
#include <hip/hip_runtime.h>
#include <hip/hip_fp16.h>
#include <math.h>

#define T_STEPS 128
#define B_SZ 256
#define AD 16
#define ZD 32
#define KM 8
#define HID 128
#define G4H 512

// ws layout (4-byte word offsets)
#define WS_WQ   0
#define WS_WI0  98304
#define WS_BS0  102400
#define WS_BS1  102912
#define WS_Q    103424
#define WS_R    104448

typedef float f32x4 __attribute__((ext_vector_type(4)));

__device__ __forceinline__ unsigned pk16(float lo, float hi) {
  unsigned a = __half_as_ushort(__float2half_rn(lo));
  unsigned b = __half_as_ushort(__float2half_rn(hi));
  return a | (b << 16);
}

__global__ void ssm_prep_kernel(const float* __restrict__ Wih0, const float* __restrict__ Whh0,
                                const float* __restrict__ Wih1, const float* __restrict__ Whh1,
                                const float* __restrict__ bih0, const float* __restrict__ bhh0,
                                const float* __restrict__ bih1, const float* __restrict__ bhh1,
                                const float* __restrict__ QL, const float* __restrict__ RL,
                                float* __restrict__ ws) {
  unsigned* wsu = (unsigned*)ws;
  int tid = blockIdx.x * blockDim.x + threadIdx.x;
  int nt = gridDim.x * blockDim.x;
  for (int j = tid; j < G4H; j += nt) {
    for (int d4 = 0; d4 < 48; ++d4) {
      for (int m = 0; m < 4; ++m) {
        int dd = (d4 & 15) * 4 + m;
        const float* src = (d4 < 16) ? Whh0 : (d4 < 32) ? Wih1 : Whh1;
        wsu[WS_WQ + (d4 * 512 + j) * 4 + m] =
            pk16(src[j * 128 + 2 * dd], src[j * 128 + 2 * dd + 1]);
      }
    }
    for (int k = 0; k < 8; ++k)
      wsu[WS_WI0 + k * 512 + j] = pk16(Wih0[j * 16 + 2 * k], Wih0[j * 16 + 2 * k + 1]);
    ws[WS_BS0 + j] = bih0[j] + bhh0[j];
    ws[WS_BS1 + j] = bih1[j] + bhh1[j];
  }
  for (int e = tid; e < ZD * ZD; e += nt) {
    int i = e >> 5, j = e & 31;
    float s = 0.f;
    for (int k = 0; k < ZD; ++k) s += QL[i * ZD + k] * QL[j * ZD + k];
    if (i == j) s += 0.001f;
    ws[WS_Q + e] = s;
  }
  for (int e = tid; e < AD * AD; e += nt) {
    int i = e >> 4, j = e & 15;
    float s = 0.f;
    for (int k = 0; k < AD; ++k) s += RL[i * AD + k] * RL[j * AD + k];
    if (i == j) s += 0.001f;
    ws[WS_R + e] = s;
  }
}

__device__ __forceinline__ float sigm(float x) { return 1.0f / (1.0f + expf(-x)); }
__device__ __forceinline__ float dotv(f32x4 a, f32x4 b) {
  return a[0] * b[0] + a[1] * b[1] + a[2] * b[2] + a[3] * b[3];
}
__device__ __forceinline__ void st_nt(float* p, float v) { __builtin_nontemporal_store(v, p); }
__device__ __forceinline__ void st_nt4(float* p, f32x4 v) {
  __builtin_nontemporal_store(v, (f32x4*)p);
}

__device__ __forceinline__ float dot2f(unsigned a, unsigned b, float c) {
#if __has_builtin(__builtin_amdgcn_fdot2)
  typedef _Float16 h2 __attribute__((ext_vector_type(2)));
  union U { unsigned u; h2 h; };
  U ua, ub; ua.u = a; ub.u = b;
  return __builtin_amdgcn_fdot2(ua.h, ub.h, c, false);
#else
  union U { unsigned u; _Float16 h[2]; };
  U ua, ub; ua.u = a; ub.u = b;
  return c + (float)ua.h[0] * (float)ub.h[0] + (float)ua.h[1] * (float)ub.h[1];
#endif
}

// ================= Kernel 1: LSTM chain, 2 batches per block (GPB=2) =================
// Thread j computes gate j for BOTH batches per weight load -> halves aggregate
// L2 weight traffic (the measured ~78 B/cy/CU stream is the LSTM wall).
struct alignas(16) LS {
  unsigned ap[2][8];       // a_t packed f16, per batch
  unsigned h0p[2][64];
  unsigned h1p[2][64];
  float g[2][G4H];
  float lgp[4][KM];        // per-wave logit partials (waves 0,1 = batch0; 2,3 = batch1)
};

__global__ void __launch_bounds__(512, 2) ssm_lstm_kernel(
    const float* __restrict__ as_, const float* __restrict__ AK, const float* __restrict__ CK,
    const float* __restrict__ Wout, const float* __restrict__ bout,
    const float* __restrict__ ws, float* __restrict__ out) {
  __shared__ LS s;
  const int tid = threadIdx.x;
  const int b0 = blockIdx.x * 2;
  const unsigned* wsu = (const unsigned*)ws;
  const uint4* Wg = (const uint4*)(wsu + WS_WQ);
  const f32x4* AK4 = (const f32x4*)AK;
  const f32x4* CK4 = (const f32x4*)CK;

  float* o_As = out + (size_t)T_STEPS * B_SZ * ZD + (size_t)T_STEPS * B_SZ * ZD * ZD +
                (size_t)T_STEPS * B_SZ * ZD + (size_t)T_STEPS * B_SZ * ZD * ZD;
  float* o_Cs = o_As + (size_t)(T_STEPS + 1) * B_SZ * ZD * ZD;
  float* o_a = o_Cs + (size_t)(T_STEPS + 1) * B_SZ * AD * ZD;

  const uint4* ap40 = (const uint4*)s.ap[0];
  const uint4* ap41 = (const uint4*)s.ap[1];
  const uint4* h0p40 = (const uint4*)s.h0p[0];
  const uint4* h0p41 = (const uint4*)s.h0p[1];
  const uint4* h1p40 = (const uint4*)s.h1p[0];
  const uint4* h1p41 = (const uint4*)s.h1p[1];

  unsigned wi0r[8];
  #pragma unroll
  for (int k = 0; k < 8; ++k) wi0r[k] = wsu[WS_WI0 + k * 512 + tid];
  const float bs0r = ws[WS_BS0 + tid];
  const float bs1r = ws[WS_BS1 + tid];
  float woutr[8];
  #pragma unroll
  for (int gi = 0; gi < KM; ++gi)
    woutr[gi] = (tid < 256) ? Wout[gi * HID + (tid & 127)] : 0.f;
  float boutr[8];
  #pragma unroll
  for (int k = 0; k < KM; ++k) boutr[k] = bout[k];

  float c0r = 0.f, c1r = 0.f;  // cell state for (batch=tid>>7, unit=tid&127), tid<256

  // ---- init ----
  if (tid < 128) { ((unsigned*)s.h0p)[tid] = 0u; ((unsigned*)s.h1p)[tid] = 0u; }
  if (tid < 32) {
    int bq = tid >> 4, i = tid & 15;
    float v = as_[(size_t)(b0 + bq) * AD + i];
    ((__half*)s.ap[bq])[i] = __float2half_rn(v);
    st_nt(&o_a[(size_t)(b0 + bq) * AD + i], v);
  }
  {  // o_As[0] both batches (w0 = ones)
    int bq = tid >> 8, e = tid & 255;
    f32x4 acc = {0.f, 0.f, 0.f, 0.f};
    #pragma unroll
    for (int k = 0; k < KM; ++k) acc += AK4[k * 256 + e];
    st_nt4(&o_As[((size_t)(b0 + bq)) * 1024 + e * 4], acc);
  }
  if (tid < 256) {  // o_Cs[0] both batches
    int bq = tid >> 7, e = tid & 127;
    f32x4 acc = {0.f, 0.f, 0.f, 0.f};
    #pragma unroll
    for (int k = 0; k < KM; ++k) acc += CK4[k * 128 + e];
    st_nt4(&o_Cs[((size_t)(b0 + bq)) * 512 + e * 4], acc);
  }
  __syncthreads();

  for (int t = 0; t < T_STEPS; ++t) {
    // A: L0 gates, both batches
    {
      float a0 = bs0r, a1 = bs0r;
      #pragma unroll
      for (int k4 = 0; k4 < 2; ++k4) {
        uint4 av0 = ap40[k4], av1 = ap41[k4];
        a0 = dot2f(av0.x, wi0r[k4 * 4 + 0], a0); a1 = dot2f(av1.x, wi0r[k4 * 4 + 0], a1);
        a0 = dot2f(av0.y, wi0r[k4 * 4 + 1], a0); a1 = dot2f(av1.y, wi0r[k4 * 4 + 1], a1);
        a0 = dot2f(av0.z, wi0r[k4 * 4 + 2], a0); a1 = dot2f(av1.z, wi0r[k4 * 4 + 2], a1);
        a0 = dot2f(av0.w, wi0r[k4 * 4 + 3], a0); a1 = dot2f(av1.w, wi0r[k4 * 4 + 3], a1);
      }
      #pragma unroll
      for (int d4 = 0; d4 < 16; ++d4) {
        uint4 w = Wg[d4 * 512 + tid];
        uint4 h0 = h0p40[d4], h1 = h0p41[d4];
        a0 = dot2f(h0.x, w.x, a0); a1 = dot2f(h1.x, w.x, a1);
        a0 = dot2f(h0.y, w.y, a0); a1 = dot2f(h1.y, w.y, a1);
        a0 = dot2f(h0.z, w.z, a0); a1 = dot2f(h1.z, w.z, a1);
        a0 = dot2f(h0.w, w.w, a0); a1 = dot2f(h1.w, w.w, a1);
      }
      s.g[0][tid] = a0;
      s.g[1][tid] = a1;
    }
    __syncthreads();

    // B: h0/c0 (thread = (batch, unit))
    if (tid < 256) {
      int ub = tid >> 7, u = tid & 127;
      float ig = sigm(s.g[ub][u]);
      float fg = sigm(s.g[ub][HID + u]);
      float gg = tanhf(s.g[ub][2 * HID + u]);
      float og = sigm(s.g[ub][3 * HID + u]);
      c0r = fg * c0r + ig * gg;
      ((__half*)s.h0p[ub])[u] = __float2half_rn(og * tanhf(c0r));
    }
    __syncthreads();

    // C: L1 gates, both batches
    {
      float a0 = bs1r, a1 = bs1r;
      #pragma unroll
      for (int d4 = 0; d4 < 16; ++d4) {
        uint4 w = Wg[(16 + d4) * 512 + tid];
        uint4 h0 = h0p40[d4], h1 = h0p41[d4];
        a0 = dot2f(h0.x, w.x, a0); a1 = dot2f(h1.x, w.x, a1);
        a0 = dot2f(h0.y, w.y, a0); a1 = dot2f(h1.y, w.y, a1);
        a0 = dot2f(h0.z, w.z, a0); a1 = dot2f(h1.z, w.z, a1);
        a0 = dot2f(h0.w, w.w, a0); a1 = dot2f(h1.w, w.w, a1);
      }
      #pragma unroll
      for (int d4 = 0; d4 < 16; ++d4) {
        uint4 w = Wg[(32 + d4) * 512 + tid];
        uint4 h0 = h1p40[d4], h1 = h1p41[d4];
        a0 = dot2f(h0.x, w.x, a0); a1 = dot2f(h1.x, w.x, a1);
        a0 = dot2f(h0.y, w.y, a0); a1 = dot2f(h1.y, w.y, a1);
        a0 = dot2f(h0.z, w.z, a0); a1 = dot2f(h1.z, w.z, a1);
        a0 = dot2f(h0.w, w.w, a0); a1 = dot2f(h1.w, w.w, a1);
      }
      s.g[0][tid] = a0;
      s.g[1][tid] = a1;
    }
    __syncthreads();

    // D: h1/c1 + logit partials (waves 0,1 = batch0; waves 2,3 = batch1)
    if (tid < 256) {
      int ub = tid >> 7, u = tid & 127;
      float ig = sigm(s.g[ub][u]);
      float fg = sigm(s.g[ub][HID + u]);
      float gg = tanhf(s.g[ub][2 * HID + u]);
      float og = sigm(s.g[ub][3 * HID + u]);
      c1r = fg * c1r + ig * gg;
      float h1u = og * tanhf(c1r);
      ((__half*)s.h1p[ub])[u] = __float2half_rn(h1u);
      int w2 = tid >> 6, lane = tid & 63;
      #pragma unroll
      for (int gi = 0; gi < KM; ++gi) {
        float p = woutr[gi] * h1u;
        #pragma unroll
        for (int m = 32; m >= 1; m >>= 1) p += __shfl_xor(p, m);
        if (lane == 0) s.lgp[w2][gi] = p;
      }
    }
    __syncthreads();

    // E: softmax (both batches, all threads) + A/C einsum outputs + a prefetch
    {
      float lg0[KM], lg1[KM];
      float mx0 = -1e30f, mx1 = -1e30f;
      #pragma unroll
      for (int k = 0; k < KM; ++k) {
        lg0[k] = s.lgp[0][k] + s.lgp[1][k] + boutr[k];
        lg1[k] = s.lgp[2][k] + s.lgp[3][k] + boutr[k];
        mx0 = fmaxf(mx0, lg0[k]);
        mx1 = fmaxf(mx1, lg1[k]);
      }
      float s0 = 0.f, s1 = 0.f;
      #pragma unroll
      for (int k = 0; k < KM; ++k) {
        lg0[k] = expf(lg0[k] - mx0); s0 += lg0[k];
        lg1[k] = expf(lg1[k] - mx1); s1 += lg1[k];
      }
      float i0 = 1.0f / s0, i1 = 1.0f / s1;
      #pragma unroll
      for (int k = 0; k < KM; ++k) { lg0[k] *= i0; lg1[k] *= i1; }

      {  // A_{t+1}: 512 threads = 2 batches x 256 f32x4
        int bq = tid >> 8, e = tid & 255;
        f32x4 acc = {0.f, 0.f, 0.f, 0.f};
        #pragma unroll
        for (int k = 0; k < KM; ++k) {
          float wk = bq ? lg1[k] : lg0[k];
          acc += wk * AK4[k * 256 + e];
        }
        st_nt4(&o_As[((size_t)(t + 1) * B_SZ + b0 + bq) * 1024 + e * 4], acc);
      }
      if (tid < 256) {  // C_{t+1}: 2 batches x 128 f32x4
        int bq = tid >> 7, e = tid & 127;
        f32x4 acc = {0.f, 0.f, 0.f, 0.f};
        #pragma unroll
        for (int k = 0; k < KM; ++k) {
          float wk = bq ? lg1[k] : lg0[k];
          acc += wk * CK4[k * 128 + e];
        }
        st_nt4(&o_Cs[((size_t)(t + 1) * B_SZ + b0 + bq) * 512 + e * 4], acc);
      } else if (tid >= 480 && t < T_STEPS - 1) {  // a_{t+1} both batches
        int idx = tid - 480, bq = idx >> 4, i = idx & 15;
        float v = as_[((size_t)(t + 1) * B_SZ + b0 + bq) * AD + i];
        ((__half*)s.ap[bq])[i] = __float2half_rn(v);
        st_nt(&o_a[((size_t)(t + 1) * B_SZ + b0 + bq) * AD + i], v);
      }
    }
    __syncthreads();
  }
}

// ===== Kernel 2: Kalman chain — 4 waves/batch; ALL global stores issued in the
// ===== final phase (single vmcnt-drain per step instead of four).
struct alignas(16) KS {
  float P[ZD * 36];
  float An[ZD * 36];
  float Mt[ZD * 36];
  float MtT[ZD * 36];
  float Sy[ZD * 36];
  float ACt[ZD * 36];
  float Qs[ZD * 36];
  float C[AD * 36];
  float Aug[AD * 52];
  float Kk[ZD * 20];
  float Rs[AD * AD];
  float meanp[ZD], meant[ZD], r[AD], af[AD];
};

__global__ void __launch_bounds__(256, 1) ssm_kalman_kernel(
    const float* __restrict__ as_, const float* __restrict__ initm,
    const float* __restrict__ initc, const float* __restrict__ ws,
    float* __restrict__ out) {
  __shared__ KS s;
  const int l = threadIdx.x;
  const int b = blockIdx.x;
  const int i32 = l & 31, cq = l >> 5;
  const int i16 = l & 15, j16 = l >> 4;

  float* o_means = out;
  float* o_covs = o_means + (size_t)T_STEPS * B_SZ * ZD;
  float* o_nmean = o_covs + (size_t)T_STEPS * B_SZ * ZD * ZD;
  float* o_ncovs = o_nmean + (size_t)T_STEPS * B_SZ * ZD;
  const float* o_As = o_ncovs + (size_t)T_STEPS * B_SZ * ZD * ZD;
  const float* o_Cs = o_As + (size_t)(T_STEPS + 1) * B_SZ * ZD * ZD;

  f32x4* P4 = (f32x4*)s.P;
  f32x4* An4 = (f32x4*)s.An;
  f32x4* Mt4 = (f32x4*)s.Mt;
  f32x4* MtT4 = (f32x4*)s.MtT;
  f32x4* Sy4 = (f32x4*)s.Sy;
  f32x4* ACt4 = (f32x4*)s.ACt;
  f32x4* Q4 = (f32x4*)s.Qs;
  f32x4* C4 = (f32x4*)s.C;
  f32x4* Aug4 = (f32x4*)s.Aug;
  f32x4* Kk4 = (f32x4*)s.Kk;
  f32x4* af4 = (f32x4*)s.af;
  const f32x4* r4 = (const f32x4*)s.r;
  const f32x4* meanp4 = (const f32x4*)s.meanp;
  const f32x4* meant4 = (const f32x4*)s.meant;

  #pragma unroll
  for (int q = 0; q < 4; ++q) {
    int e = q * 256 + l;
    s.P[(e >> 5) * 36 + (e & 31)] = initc[e];
    s.Qs[(e >> 5) * 36 + (e & 31)] = ws[WS_Q + e];
  }
  s.Rs[l] = ws[WS_R + l];
  if (l < ZD) s.meanp[l] = initm[l];
  {
    const f32x4* gc = (const f32x4*)&o_Cs[(size_t)b * 512];
    if (l < 128) C4[(l >> 3) * 9 + (l & 7)] = gc[l];
    const f32x4* ga = (const f32x4*)&o_As[((size_t)B_SZ + b) * 1024];
    An4[(l >> 3) * 9 + (l & 7)] = ga[l];
    if (l < 4) af4[l] = ((const f32x4*)&as_[(size_t)b * AD])[l];
  }
  __syncthreads();

  for (int t = 0; t < T_STEPS; ++t) {
    const size_t tb = (size_t)t * B_SZ + b;
    const bool pf = (t < T_STEPS - 1);

    // P0: issue prefetch (registers; committed in P8)
    f32x4 pfC = {0, 0, 0, 0};
    f32x4 pfA = {0, 0, 0, 0};
    f32x4 pfa = {0, 0, 0, 0};
    if (pf) {
      if (l >= 128) pfC = ((const f32x4*)&o_Cs[(tb + B_SZ) * 512])[l - 128];
      pfA = ((const f32x4*)&o_As[(tb + 2 * B_SZ) * 1024])[l];
      if (l < 4) pfa = ((const f32x4*)&as_[(tb + B_SZ) * AD])[l];
    }

    // deferred-store registers (carried across barriers; stored in P8)
    float meant_r = 0.f, nmean_r = 0.f;
    f32x4 covs_r = {0, 0, 0, 0};

    // P1: CP = C @ P -> Aug right half
    {
      float a0 = 0.f, a1 = 0.f;
      #pragma unroll
      for (int k4 = 0; k4 < 8; ++k4) {
        f32x4 cr = C4[i16 * 9 + k4];
        a0 += dotv(cr, P4[j16 * 9 + k4]);
        a1 += dotv(cr, P4[(j16 + 16) * 9 + k4]);
      }
      s.Aug[i16 * 52 + AD + j16] = a0;
      s.Aug[i16 * 52 + AD + j16 + 16] = a1;
    }
    __syncthreads();

    // P2: S = CP C^T + R -> Aug left; r
    {
      float acc = s.Rs[i16 * AD + j16];
      #pragma unroll
      for (int k4 = 0; k4 < 8; ++k4)
        acc += dotv(Aug4[i16 * 13 + 4 + k4], C4[j16 * 9 + k4]);
      s.Aug[i16 * 52 + j16] = acc;
      if (l >= 240) {
        int ii = l - 240;
        float rr = s.af[ii];
        #pragma unroll
        for (int k4 = 0; k4 < 8; ++k4) rr -= dotv(C4[ii * 9 + k4], meanp4[k4]);
        s.r[ii] = rr;
      }
    }
    __syncthreads();

    // P3: wave 0 GJ -> K  |  threads 128..255 commit prefetched C
    if (l < 64) {
      const int lc = (l < 48) ? l : 47;
      float col[16];
      #pragma unroll
      for (int i = 0; i < AD; ++i) col[i] = s.Aug[i * 52 + lc];
      #pragma unroll
      for (int j = 0; j < AD; ++j) {
        float pd = __shfl(col[j], j);
        float pinv = 1.0f / pd;
        float oldj = col[j];
        #pragma unroll
        for (int i = 0; i < AD; ++i) {
          if (i == j) continue;
          float fi = __shfl(col[i], j);
          col[i] = fmaf(-(fi * pinv), oldj, col[i]);
        }
        col[j] = oldj * pinv;
      }
      if (l >= AD && l < AD + ZD) {
        int rr = l - AD;
        f32x4 v0 = {col[0], col[1], col[2], col[3]};
        f32x4 v1 = {col[4], col[5], col[6], col[7]};
        f32x4 v2 = {col[8], col[9], col[10], col[11]};
        f32x4 v3 = {col[12], col[13], col[14], col[15]};
        Kk4[rr * 5 + 0] = v0;
        Kk4[rr * 5 + 1] = v1;
        Kk4[rr * 5 + 2] = v2;
        Kk4[rr * 5 + 3] = v3;
      }
    } else if (pf && l >= 128) {
      int idx = l - 128;
      C4[(idx >> 3) * 9 + (idx & 7)] = pfC;
    }
    __syncthreads();

    // P4: cov_t = P - K@CP -> Mt, MtT
    {
      f32x4 acc = {0.f, 0.f, 0.f, 0.f};
      #pragma unroll
      for (int k4 = 0; k4 < 4; ++k4) {
        f32x4 kv = Kk4[i32 * 5 + k4];
        #pragma unroll
        for (int kk = 0; kk < 4; ++kk) {
          f32x4 cpk = Aug4[(4 * k4 + kk) * 13 + 4 + cq];
          acc += kv[kk] * cpk;
        }
      }
      f32x4 mv = P4[i32 * 9 + cq] - acc;
      Mt4[i32 * 9 + cq] = mv;
      #pragma unroll
      for (int jj = 0; jj < 4; ++jj) s.MtT[(4 * cq + jj) * 36 + i32] = mv[jj];
    }
    __syncthreads();

    // P5: Sy = 0.5(Mt+MtT) (reg-kept for store); mean_t (reg-kept)
    {
      covs_r = 0.5f * (Mt4[i32 * 9 + cq] + MtT4[i32 * 9 + cq]);
      Sy4[i32 * 9 + cq] = covs_r;
      if (l < ZD) {
        float acc = s.meanp[l];
        #pragma unroll
        for (int m = 0; m < 4; ++m) acc += dotv(Kk4[l * 5 + m], r4[m]);
        s.meant[l] = acc;
        meant_r = acc;
      }
    }
    __syncthreads();

    // P6: ACt = An @ Sy
    {
      float c0 = 0.f, c1 = 0.f, c2 = 0.f, c3 = 0.f;
      #pragma unroll
      for (int k4 = 0; k4 < 8; ++k4) {
        f32x4 an = An4[i32 * 9 + k4];
        c0 += dotv(an, Sy4[(4 * cq + 0) * 9 + k4]);
        c1 += dotv(an, Sy4[(4 * cq + 1) * 9 + k4]);
        c2 += dotv(an, Sy4[(4 * cq + 2) * 9 + k4]);
        c3 += dotv(an, Sy4[(4 * cq + 3) * 9 + k4]);
      }
      f32x4 v = {c0, c1, c2, c3};
      ACt4[i32 * 9 + cq] = v;
    }
    __syncthreads();

    // P7: M2 = ACt @ An^T -> Mt/MtT; meanp' (reg-kept)
    {
      if (l < ZD) {
        float acc = 0.f;
        #pragma unroll
        for (int k4 = 0; k4 < 8; ++k4) acc += dotv(An4[l * 9 + k4], meant4[k4]);
        s.meanp[l] = acc;
        nmean_r = acc;
      }
      float c0 = 0.f, c1 = 0.f, c2 = 0.f, c3 = 0.f;
      #pragma unroll
      for (int k4 = 0; k4 < 8; ++k4) {
        f32x4 ac = ACt4[i32 * 9 + k4];
        c0 += dotv(ac, An4[(4 * cq + 0) * 9 + k4]);
        c1 += dotv(ac, An4[(4 * cq + 1) * 9 + k4]);
        c2 += dotv(ac, An4[(4 * cq + 2) * 9 + k4]);
        c3 += dotv(ac, An4[(4 * cq + 3) * 9 + k4]);
      }
      f32x4 mv = {c0, c1, c2, c3};
      Mt4[i32 * 9 + cq] = mv;
      #pragma unroll
      for (int jj = 0; jj < 4; ++jj) s.MtT[(4 * cq + jj) * 36 + i32] = mv[jj];
    }
    __syncthreads();

    // P8: P' = 0.5(M2+M2^T) + Q -> P; THEN issue all global stores (one drain);
    //     commit prefetched An/a (C committed in P3).
    {
      f32x4 pv = 0.5f * (Mt4[i32 * 9 + cq] + MtT4[i32 * 9 + cq]) + Q4[i32 * 9 + cq];
      P4[i32 * 9 + cq] = pv;
      st_nt4(&o_ncovs[tb * 1024 + i32 * 32 + cq * 4], pv);
      st_nt4(&o_covs[tb * 1024 + i32 * 32 + cq * 4], covs_r);
      if (l < ZD) {
        st_nt(&o_means[tb * ZD + l], meant_r);
        st_nt(&o_nmean[tb * ZD + l], nmean_r);
      }
      if (pf) {
        An4[(l >> 3) * 9 + (l & 7)] = pfA;
        if (l < 4) af4[l] = pfa;
      }
    }
    __syncthreads();
  }
}

extern "C" void kernel_launch(void* const* d_in, const int* in_sizes, int n_in,
                              void* d_out, int out_size, void* d_ws, size_t ws_size,
                              hipStream_t stream) {
  const float* as_ = (const float*)d_in[0];
  const float* AK = (const float*)d_in[1];
  const float* CK = (const float*)d_in[2];
  const float* QL = (const float*)d_in[3];
  const float* RL = (const float*)d_in[4];
  const float* initm = (const float*)d_in[5];
  const float* initc = (const float*)d_in[6];
  const float* Wih0 = (const float*)d_in[7];
  const float* Whh0 = (const float*)d_in[8];
  const float* bih0 = (const float*)d_in[9];
  const float* bhh0 = (const float*)d_in[10];
  const float* Wih1 = (const float*)d_in[11];
  const float* Whh1 = (const float*)d_in[12];
  const float* bih1 = (const float*)d_in[13];
  const float* bhh1 = (const float*)d_in[14];
  const float* Wout = (const float*)d_in[15];
  const float* bout = (const float*)d_in[16];
  float* ws = (float*)d_ws;
  float* out = (float*)d_out;

  ssm_prep_kernel<<<16, 256, 0, stream>>>(Wih0, Whh0, Wih1, Whh1, bih0, bhh0, bih1, bhh1,
                                          QL, RL, ws);
  ssm_lstm_kernel<<<B_SZ / 2, 512, 0, stream>>>(as_, AK, CK, Wout, bout, ws, out);
  ssm_kalman_kernel<<<B_SZ, 256, 0, stream>>>(as_, initm, initc, ws, out);
}

// Round 18
// 1683.439 us; speedup vs baseline: 3.4251x; 1.3779x over previous
//
#include <hip/hip_runtime.h>
#include <hip/hip_fp16.h>
#include <math.h>

#define T_STEPS 128
#define B_SZ 256
#define AD 16
#define ZD 32
#define KM 8
#define HID 128
#define G4H 512
#define NTHR 512

// ws layout (4-byte word offsets)
#define WS_WQ   0
#define WS_WI0  98304
#define WS_BS0  102400
#define WS_BS1  102912
#define WS_Q    103424
#define WS_R    104448

typedef float f32x4 __attribute__((ext_vector_type(4)));

__device__ __forceinline__ unsigned pk16(float lo, float hi) {
  unsigned a = __half_as_ushort(__float2half_rn(lo));
  unsigned b = __half_as_ushort(__float2half_rn(hi));
  return a | (b << 16);
}

__global__ void ssm_prep_kernel(const float* __restrict__ Wih0, const float* __restrict__ Whh0,
                                const float* __restrict__ Wih1, const float* __restrict__ Whh1,
                                const float* __restrict__ bih0, const float* __restrict__ bhh0,
                                const float* __restrict__ bih1, const float* __restrict__ bhh1,
                                const float* __restrict__ QL, const float* __restrict__ RL,
                                float* __restrict__ ws) {
  unsigned* wsu = (unsigned*)ws;
  int tid = blockIdx.x * blockDim.x + threadIdx.x;
  int nt = gridDim.x * blockDim.x;
  for (int j = tid; j < G4H; j += nt) {
    for (int d4 = 0; d4 < 48; ++d4) {
      for (int m = 0; m < 4; ++m) {
        int dd = (d4 & 15) * 4 + m;
        const float* src = (d4 < 16) ? Whh0 : (d4 < 32) ? Wih1 : Whh1;
        wsu[WS_WQ + (d4 * 512 + j) * 4 + m] =
            pk16(src[j * 128 + 2 * dd], src[j * 128 + 2 * dd + 1]);
      }
    }
    for (int k = 0; k < 8; ++k)
      wsu[WS_WI0 + k * 512 + j] = pk16(Wih0[j * 16 + 2 * k], Wih0[j * 16 + 2 * k + 1]);
    ws[WS_BS0 + j] = bih0[j] + bhh0[j];
    ws[WS_BS1 + j] = bih1[j] + bhh1[j];
  }
  for (int e = tid; e < ZD * ZD; e += nt) {
    int i = e >> 5, j = e & 31;
    float s = 0.f;
    for (int k = 0; k < ZD; ++k) s += QL[i * ZD + k] * QL[j * ZD + k];
    if (i == j) s += 0.001f;
    ws[WS_Q + e] = s;
  }
  for (int e = tid; e < AD * AD; e += nt) {
    int i = e >> 4, j = e & 15;
    float s = 0.f;
    for (int k = 0; k < AD; ++k) s += RL[i * AD + k] * RL[j * AD + k];
    if (i == j) s += 0.001f;
    ws[WS_R + e] = s;
  }
}

__device__ __forceinline__ float sigm(float x) { return 1.0f / (1.0f + expf(-x)); }
__device__ __forceinline__ float dotv(f32x4 a, f32x4 b) {
  return a[0] * b[0] + a[1] * b[1] + a[2] * b[2] + a[3] * b[3];
}
__device__ __forceinline__ void st_nt(float* p, float v) { __builtin_nontemporal_store(v, p); }
__device__ __forceinline__ void st_nt4(float* p, f32x4 v) {
  __builtin_nontemporal_store(v, (f32x4*)p);
}

__device__ __forceinline__ float dot2f(unsigned a, unsigned b, float c) {
#if __has_builtin(__builtin_amdgcn_fdot2)
  typedef _Float16 h2 __attribute__((ext_vector_type(2)));
  union U { unsigned u; h2 h; };
  U ua, ub; ua.u = a; ub.u = b;
  return __builtin_amdgcn_fdot2(ua.h, ub.h, c, false);
#else
  union U { unsigned u; _Float16 h[2]; };
  U ua, ub; ua.u = a; ub.u = b;
  return c + (float)ua.h[0] * (float)ub.h[0] + (float)ua.h[1] * (float)ub.h[1];
#endif
}

// ============================ Kernel 1: LSTM chain (GPB=1, round-14 proven) ============================
struct alignas(16) LS {
  unsigned ap[8];
  unsigned h0p[64];
  unsigned h1p[64];
  float g[G4H];
  float lgp[16];
};

__global__ void __launch_bounds__(NTHR, 2) ssm_lstm_kernel(
    const float* __restrict__ as_, const float* __restrict__ AK, const float* __restrict__ CK,
    const float* __restrict__ Wout, const float* __restrict__ bout,
    const float* __restrict__ ws, float* __restrict__ out) {
  __shared__ LS s;
  const int tid = threadIdx.x;
  const int b = blockIdx.x;
  const unsigned* wsu = (const unsigned*)ws;
  const uint4* Wg = (const uint4*)(wsu + WS_WQ);
  const f32x4* AK4 = (const f32x4*)AK;
  const f32x4* CK4 = (const f32x4*)CK;

  float* o_As = out + (size_t)T_STEPS * B_SZ * ZD + (size_t)T_STEPS * B_SZ * ZD * ZD +
                (size_t)T_STEPS * B_SZ * ZD + (size_t)T_STEPS * B_SZ * ZD * ZD;
  float* o_Cs = o_As + (size_t)(T_STEPS + 1) * B_SZ * ZD * ZD;
  float* o_a = o_Cs + (size_t)(T_STEPS + 1) * B_SZ * AD * ZD;

  const uint4* h0p4 = (const uint4*)s.h0p;
  const uint4* h1p4 = (const uint4*)s.h1p;
  const uint4* ap4 = (const uint4*)s.ap;

  unsigned wi0r[8];
  #pragma unroll
  for (int k = 0; k < 8; ++k) wi0r[k] = wsu[WS_WI0 + k * 512 + tid];
  const float bs0r = ws[WS_BS0 + tid];
  const float bs1r = ws[WS_BS1 + tid];
  float woutr[8];
  #pragma unroll
  for (int gi = 0; gi < KM; ++gi) woutr[gi] = (tid < HID) ? Wout[gi * HID + tid] : 0.f;
  float boutr[8];
  #pragma unroll
  for (int k = 0; k < KM; ++k) boutr[k] = bout[k];

  float c0r = 0.f, c1r = 0.f;

  if (tid < 64) { s.h0p[tid] = 0u; s.h1p[tid] = 0u; }
  if (tid < AD) {
    float v = as_[(size_t)b * AD + tid];
    ((__half*)s.ap)[tid] = __float2half_rn(v);
    st_nt(&o_a[(size_t)b * AD + tid], v);
  }
  if (tid < 256) {
    f32x4 acc = {0.f, 0.f, 0.f, 0.f};
    #pragma unroll
    for (int k = 0; k < KM; ++k) acc += AK4[k * 256 + tid];
    st_nt4(&o_As[(size_t)b * 1024 + tid * 4], acc);
  } else if (tid < 384) {
    int idx = tid - 256;
    f32x4 acc = {0.f, 0.f, 0.f, 0.f};
    #pragma unroll
    for (int k = 0; k < KM; ++k) acc += CK4[k * 128 + idx];
    st_nt4(&o_Cs[(size_t)b * 512 + idx * 4], acc);
  }
  __syncthreads();

  for (int t = 0; t < T_STEPS; ++t) {
    const size_t tb2 = (size_t)(t + 1) * B_SZ + b;

    {  // A: L0 gates (stream W_hh0)
      float acc = bs0r;
      #pragma unroll
      for (int k4 = 0; k4 < 2; ++k4) {
        uint4 av = ap4[k4];
        acc = dot2f(av.x, wi0r[k4 * 4 + 0], acc);
        acc = dot2f(av.y, wi0r[k4 * 4 + 1], acc);
        acc = dot2f(av.z, wi0r[k4 * 4 + 2], acc);
        acc = dot2f(av.w, wi0r[k4 * 4 + 3], acc);
      }
      #pragma unroll
      for (int d4 = 0; d4 < 16; ++d4) {
        uint4 w = Wg[d4 * 512 + tid];
        uint4 hv = h0p4[d4];
        acc = dot2f(hv.x, w.x, acc);
        acc = dot2f(hv.y, w.y, acc);
        acc = dot2f(hv.z, w.z, acc);
        acc = dot2f(hv.w, w.w, acc);
      }
      s.g[tid] = acc;
    }
    __syncthreads();

    if (tid < HID) {  // B: h0/c0
      float ig = sigm(s.g[tid]);
      float fg = sigm(s.g[HID + tid]);
      float gg = tanhf(s.g[2 * HID + tid]);
      float og = sigm(s.g[3 * HID + tid]);
      c0r = fg * c0r + ig * gg;
      ((__half*)s.h0p)[tid] = __float2half_rn(og * tanhf(c0r));
    }
    __syncthreads();

    {  // C: L1 gates (stream W_ih1 + W_hh1)
      float acc = bs1r;
      #pragma unroll
      for (int d4 = 0; d4 < 16; ++d4) {
        uint4 w = Wg[(16 + d4) * 512 + tid];
        uint4 hv = h0p4[d4];
        acc = dot2f(hv.x, w.x, acc);
        acc = dot2f(hv.y, w.y, acc);
        acc = dot2f(hv.z, w.z, acc);
        acc = dot2f(hv.w, w.w, acc);
      }
      #pragma unroll
      for (int d4 = 0; d4 < 16; ++d4) {
        uint4 w = Wg[(32 + d4) * 512 + tid];
        uint4 hv = h1p4[d4];
        acc = dot2f(hv.x, w.x, acc);
        acc = dot2f(hv.y, w.y, acc);
        acc = dot2f(hv.z, w.z, acc);
        acc = dot2f(hv.w, w.w, acc);
      }
      s.g[tid] = acc;
    }
    __syncthreads();

    if (tid < HID) {  // D: h1/c1 + logit partials
      float ig = sigm(s.g[tid]);
      float fg = sigm(s.g[HID + tid]);
      float gg = tanhf(s.g[2 * HID + tid]);
      float og = sigm(s.g[3 * HID + tid]);
      c1r = fg * c1r + ig * gg;
      float h1u = og * tanhf(c1r);
      ((__half*)s.h1p)[tid] = __float2half_rn(h1u);
      int w2 = tid >> 6, lane = tid & 63;
      #pragma unroll
      for (int gi = 0; gi < KM; ++gi) {
        float p = woutr[gi] * h1u;
        #pragma unroll
        for (int m = 32; m >= 1; m >>= 1) p += __shfl_xor(p, m);
        if (lane == 0) s.lgp[w2 * KM + gi] = p;
      }
    }
    __syncthreads();

    {  // E: softmax + einsum outputs + a prefetch
      float lg[KM];
      float mx = -1e30f;
      #pragma unroll
      for (int k = 0; k < KM; ++k) {
        lg[k] = s.lgp[k] + s.lgp[KM + k] + boutr[k];
        mx = fmaxf(mx, lg[k]);
      }
      float sum = 0.f;
      #pragma unroll
      for (int k = 0; k < KM; ++k) { lg[k] = expf(lg[k] - mx); sum += lg[k]; }
      float inv = 1.0f / sum;
      #pragma unroll
      for (int k = 0; k < KM; ++k) lg[k] *= inv;
      if (tid < 256) {
        f32x4 acc = {0.f, 0.f, 0.f, 0.f};
        #pragma unroll
        for (int k = 0; k < KM; ++k) acc += lg[k] * AK4[k * 256 + tid];
        st_nt4(&o_As[tb2 * 1024 + tid * 4], acc);
      } else if (tid < 384) {
        int idx = tid - 256;
        f32x4 acc = {0.f, 0.f, 0.f, 0.f};
        #pragma unroll
        for (int k = 0; k < KM; ++k) acc += lg[k] * CK4[k * 128 + idx];
        st_nt4(&o_Cs[tb2 * 512 + idx * 4], acc);
      } else if (tid >= 448 && tid < 448 + AD && t < T_STEPS - 1) {
        int i = tid - 448;
        float v = as_[tb2 * AD + i];
        ((__half*)s.ap)[i] = __float2half_rn(v);
        st_nt(&o_a[tb2 * AD + i], v);
      }
    }
    __syncthreads();
  }
}

// ===== Kernel 2: Kalman — 4 waves/batch, 7 barriers/step (mean_t in P4; Sy folded
// ===== into ACt on the fly), all global stores deferred to the final phase.
struct alignas(16) KS {
  float P[ZD * 36];
  float An[ZD * 36];
  float Mt[ZD * 36];
  float MtT[ZD * 36];
  float ACt[ZD * 36];
  float Qs[ZD * 36];
  float C[AD * 36];
  float Aug[AD * 52];
  float Kk[ZD * 20];
  float Rs[AD * AD];
  float meanp[ZD], meant[ZD], r[AD], af[AD];
};

__global__ void __launch_bounds__(256, 1) ssm_kalman_kernel(
    const float* __restrict__ as_, const float* __restrict__ initm,
    const float* __restrict__ initc, const float* __restrict__ ws,
    float* __restrict__ out) {
  __shared__ KS s;
  const int l = threadIdx.x;
  const int b = blockIdx.x;
  const int i32 = l & 31, cq = l >> 5;
  const int i16 = l & 15, j16 = l >> 4;

  float* o_means = out;
  float* o_covs = o_means + (size_t)T_STEPS * B_SZ * ZD;
  float* o_nmean = o_covs + (size_t)T_STEPS * B_SZ * ZD * ZD;
  float* o_ncovs = o_nmean + (size_t)T_STEPS * B_SZ * ZD;
  const float* o_As = o_ncovs + (size_t)T_STEPS * B_SZ * ZD * ZD;
  const float* o_Cs = o_As + (size_t)(T_STEPS + 1) * B_SZ * ZD * ZD;

  f32x4* P4 = (f32x4*)s.P;
  f32x4* An4 = (f32x4*)s.An;
  f32x4* Mt4 = (f32x4*)s.Mt;
  f32x4* MtT4 = (f32x4*)s.MtT;
  f32x4* ACt4 = (f32x4*)s.ACt;
  f32x4* Q4 = (f32x4*)s.Qs;
  f32x4* C4 = (f32x4*)s.C;
  f32x4* Aug4 = (f32x4*)s.Aug;
  f32x4* Kk4 = (f32x4*)s.Kk;
  f32x4* af4 = (f32x4*)s.af;
  const f32x4* r4 = (const f32x4*)s.r;
  const f32x4* meanp4 = (const f32x4*)s.meanp;
  const f32x4* meant4 = (const f32x4*)s.meant;

  #pragma unroll
  for (int q = 0; q < 4; ++q) {
    int e = q * 256 + l;
    s.P[(e >> 5) * 36 + (e & 31)] = initc[e];
    s.Qs[(e >> 5) * 36 + (e & 31)] = ws[WS_Q + e];
  }
  s.Rs[l] = ws[WS_R + l];
  if (l < ZD) s.meanp[l] = initm[l];
  {
    const f32x4* gc = (const f32x4*)&o_Cs[(size_t)b * 512];
    if (l < 128) C4[(l >> 3) * 9 + (l & 7)] = gc[l];
    const f32x4* ga = (const f32x4*)&o_As[((size_t)B_SZ + b) * 1024];
    An4[(l >> 3) * 9 + (l & 7)] = ga[l];
    if (l < 4) af4[l] = ((const f32x4*)&as_[(size_t)b * AD])[l];
  }
  __syncthreads();

  for (int t = 0; t < T_STEPS; ++t) {
    const size_t tb = (size_t)t * B_SZ + b;
    const bool pf = (t < T_STEPS - 1);

    // P0: issue prefetch (registers; C committed in P3, An/a in final phase)
    f32x4 pfC = {0, 0, 0, 0};
    f32x4 pfA = {0, 0, 0, 0};
    f32x4 pfa = {0, 0, 0, 0};
    if (pf) {
      if (l >= 128) pfC = ((const f32x4*)&o_Cs[(tb + B_SZ) * 512])[l - 128];
      pfA = ((const f32x4*)&o_As[(tb + 2 * B_SZ) * 1024])[l];
      if (l < 4) pfa = ((const f32x4*)&as_[(tb + B_SZ) * AD])[l];
    }

    // deferred-store registers
    float meant_r = 0.f, nmean_r = 0.f;
    f32x4 covs_r = {0, 0, 0, 0};

    // P1: CP = C @ P -> Aug right half
    {
      float a0 = 0.f, a1 = 0.f;
      #pragma unroll
      for (int k4 = 0; k4 < 8; ++k4) {
        f32x4 cr = C4[i16 * 9 + k4];
        a0 += dotv(cr, P4[j16 * 9 + k4]);
        a1 += dotv(cr, P4[(j16 + 16) * 9 + k4]);
      }
      s.Aug[i16 * 52 + AD + j16] = a0;
      s.Aug[i16 * 52 + AD + j16 + 16] = a1;
    }
    __syncthreads();

    // P2: S = CP C^T + R -> Aug left; r
    {
      float acc = s.Rs[i16 * AD + j16];
      #pragma unroll
      for (int k4 = 0; k4 < 8; ++k4)
        acc += dotv(Aug4[i16 * 13 + 4 + k4], C4[j16 * 9 + k4]);
      s.Aug[i16 * 52 + j16] = acc;
      if (l >= 240) {
        int ii = l - 240;
        float rr = s.af[ii];
        #pragma unroll
        for (int k4 = 0; k4 < 8; ++k4) rr -= dotv(C4[ii * 9 + k4], meanp4[k4]);
        s.r[ii] = rr;
      }
    }
    __syncthreads();

    // P3: wave 0 GJ -> K  |  threads 128..255 commit prefetched C
    if (l < 64) {
      const int lc = (l < 48) ? l : 47;
      float col[16];
      #pragma unroll
      for (int i = 0; i < AD; ++i) col[i] = s.Aug[i * 52 + lc];
      #pragma unroll
      for (int j = 0; j < AD; ++j) {
        float pd = __shfl(col[j], j);
        float pinv = 1.0f / pd;
        float oldj = col[j];
        #pragma unroll
        for (int i = 0; i < AD; ++i) {
          if (i == j) continue;
          float fi = __shfl(col[i], j);
          col[i] = fmaf(-(fi * pinv), oldj, col[i]);
        }
        col[j] = oldj * pinv;
      }
      if (l >= AD && l < AD + ZD) {
        int rr = l - AD;
        f32x4 v0 = {col[0], col[1], col[2], col[3]};
        f32x4 v1 = {col[4], col[5], col[6], col[7]};
        f32x4 v2 = {col[8], col[9], col[10], col[11]};
        f32x4 v3 = {col[12], col[13], col[14], col[15]};
        Kk4[rr * 5 + 0] = v0;
        Kk4[rr * 5 + 1] = v1;
        Kk4[rr * 5 + 2] = v2;
        Kk4[rr * 5 + 3] = v3;
      }
    } else if (pf && l >= 128) {
      int idx = l - 128;
      C4[(idx >> 3) * 9 + (idx & 7)] = pfC;
    }
    __syncthreads();

    // P4: cov_t = P - K@CP -> Mt, MtT; mean_t (reg-kept + LDS for nmean)
    {
      if (l < ZD) {
        float acc = s.meanp[l];
        #pragma unroll
        for (int m = 0; m < 4; ++m) acc += dotv(Kk4[l * 5 + m], r4[m]);
        s.meant[l] = acc;
        meant_r = acc;
      }
      f32x4 acc = {0.f, 0.f, 0.f, 0.f};
      #pragma unroll
      for (int k4 = 0; k4 < 4; ++k4) {
        f32x4 kv = Kk4[i32 * 5 + k4];
        #pragma unroll
        for (int kk = 0; kk < 4; ++kk) {
          f32x4 cpk = Aug4[(4 * k4 + kk) * 13 + 4 + cq];
          acc += kv[kk] * cpk;
        }
      }
      f32x4 mv = P4[i32 * 9 + cq] - acc;
      Mt4[i32 * 9 + cq] = mv;
      #pragma unroll
      for (int jj = 0; jj < 4; ++jj) s.MtT[(4 * cq + jj) * 36 + i32] = mv[jj];
    }
    __syncthreads();

    // P5: ACt = An @ sym(Mt,MtT) on the fly; covs_r; nmean_r  (Sy phase eliminated)
    {
      covs_r = 0.5f * (Mt4[i32 * 9 + cq] + MtT4[i32 * 9 + cq]);
      if (l < ZD) {
        float acc = 0.f;
        #pragma unroll
        for (int k4 = 0; k4 < 8; ++k4) acc += dotv(An4[l * 9 + k4], meant4[k4]);
        nmean_r = acc;
        s.meanp[l] = acc;
      }
      float c0 = 0.f, c1 = 0.f, c2 = 0.f, c3 = 0.f;
      #pragma unroll
      for (int k4 = 0; k4 < 8; ++k4) {
        f32x4 an = An4[i32 * 9 + k4];
        f32x4 sy0 = 0.5f * (Mt4[(4 * cq + 0) * 9 + k4] + MtT4[(4 * cq + 0) * 9 + k4]);
        f32x4 sy1 = 0.5f * (Mt4[(4 * cq + 1) * 9 + k4] + MtT4[(4 * cq + 1) * 9 + k4]);
        f32x4 sy2 = 0.5f * (Mt4[(4 * cq + 2) * 9 + k4] + MtT4[(4 * cq + 2) * 9 + k4]);
        f32x4 sy3 = 0.5f * (Mt4[(4 * cq + 3) * 9 + k4] + MtT4[(4 * cq + 3) * 9 + k4]);
        c0 += dotv(an, sy0);
        c1 += dotv(an, sy1);
        c2 += dotv(an, sy2);
        c3 += dotv(an, sy3);
      }
      f32x4 v = {c0, c1, c2, c3};
      ACt4[i32 * 9 + cq] = v;
    }
    __syncthreads();

    // P6: M2 = ACt @ An^T -> Mt/MtT
    {
      float c0 = 0.f, c1 = 0.f, c2 = 0.f, c3 = 0.f;
      #pragma unroll
      for (int k4 = 0; k4 < 8; ++k4) {
        f32x4 ac = ACt4[i32 * 9 + k4];
        c0 += dotv(ac, An4[(4 * cq + 0) * 9 + k4]);
        c1 += dotv(ac, An4[(4 * cq + 1) * 9 + k4]);
        c2 += dotv(ac, An4[(4 * cq + 2) * 9 + k4]);
        c3 += dotv(ac, An4[(4 * cq + 3) * 9 + k4]);
      }
      f32x4 mv = {c0, c1, c2, c3};
      Mt4[i32 * 9 + cq] = mv;
      #pragma unroll
      for (int jj = 0; jj < 4; ++jj) s.MtT[(4 * cq + jj) * 36 + i32] = mv[jj];
    }
    __syncthreads();

    // P7: P' = 0.5(M2+M2^T) + Q -> P; all global stores (single drain);
    //     commit prefetched An/a.
    {
      f32x4 pv = 0.5f * (Mt4[i32 * 9 + cq] + MtT4[i32 * 9 + cq]) + Q4[i32 * 9 + cq];
      P4[i32 * 9 + cq] = pv;
      st_nt4(&o_ncovs[tb * 1024 + i32 * 32 + cq * 4], pv);
      st_nt4(&o_covs[tb * 1024 + i32 * 32 + cq * 4], covs_r);
      if (l < ZD) {
        st_nt(&o_means[tb * ZD + l], meant_r);
        st_nt(&o_nmean[tb * ZD + l], nmean_r);
      }
      if (pf) {
        An4[(l >> 3) * 9 + (l & 7)] = pfA;
        if (l < 4) af4[l] = pfa;
      }
    }
    __syncthreads();
  }
}

extern "C" void kernel_launch(void* const* d_in, const int* in_sizes, int n_in,
                              void* d_out, int out_size, void* d_ws, size_t ws_size,
                              hipStream_t stream) {
  const float* as_ = (const float*)d_in[0];
  const float* AK = (const float*)d_in[1];
  const float* CK = (const float*)d_in[2];
  const float* QL = (const float*)d_in[3];
  const float* RL = (const float*)d_in[4];
  const float* initm = (const float*)d_in[5];
  const float* initc = (const float*)d_in[6];
  const float* Wih0 = (const float*)d_in[7];
  const float* Whh0 = (const float*)d_in[8];
  const float* bih0 = (const float*)d_in[9];
  const float* bhh0 = (const float*)d_in[10];
  const float* Wih1 = (const float*)d_in[11];
  const float* Whh1 = (const float*)d_in[12];
  const float* bih1 = (const float*)d_in[13];
  const float* bhh1 = (const float*)d_in[14];
  const float* Wout = (const float*)d_in[15];
  const float* bout = (const float*)d_in[16];
  float* ws = (float*)d_ws;
  float* out = (float*)d_out;

  ssm_prep_kernel<<<16, 256, 0, stream>>>(Wih0, Whh0, Wih1, Whh1, bih0, bhh0, bih1, bhh1,
                                          QL, RL, ws);
  ssm_lstm_kernel<<<B_SZ, NTHR, 0, stream>>>(as_, AK, CK, Wout, bout, ws, out);
  ssm_kalman_kernel<<<B_SZ, 256, 0, stream>>>(as_, initm, initc, ws, out);
}

// Round 19
// 1628.086 us; speedup vs baseline: 3.5415x; 1.0340x over previous
//
#include <hip/hip_runtime.h>
#include <hip/hip_fp16.h>
#include <math.h>

#define T_STEPS 128
#define B_SZ 256
#define AD 16
#define ZD 32
#define KM 8
#define HID 128
#define G4H 512
#define NTHR 512

// ws layout (4-byte word offsets)
#define WS_WQ   0
#define WS_WI0  98304
#define WS_BS0  102400
#define WS_BS1  102912
#define WS_Q    103424
#define WS_R    104448

typedef float f32x4 __attribute__((ext_vector_type(4)));

__device__ __forceinline__ unsigned pk16(float lo, float hi) {
  unsigned a = __half_as_ushort(__float2half_rn(lo));
  unsigned b = __half_as_ushort(__float2half_rn(hi));
  return a | (b << 16);
}

__global__ void ssm_prep_kernel(const float* __restrict__ Wih0, const float* __restrict__ Whh0,
                                const float* __restrict__ Wih1, const float* __restrict__ Whh1,
                                const float* __restrict__ bih0, const float* __restrict__ bhh0,
                                const float* __restrict__ bih1, const float* __restrict__ bhh1,
                                const float* __restrict__ QL, const float* __restrict__ RL,
                                float* __restrict__ ws) {
  unsigned* wsu = (unsigned*)ws;
  int tid = blockIdx.x * blockDim.x + threadIdx.x;
  int nt = gridDim.x * blockDim.x;
  for (int j = tid; j < G4H; j += nt) {
    for (int d4 = 0; d4 < 48; ++d4) {
      for (int m = 0; m < 4; ++m) {
        int dd = (d4 & 15) * 4 + m;
        const float* src = (d4 < 16) ? Whh0 : (d4 < 32) ? Wih1 : Whh1;
        wsu[WS_WQ + (d4 * 512 + j) * 4 + m] =
            pk16(src[j * 128 + 2 * dd], src[j * 128 + 2 * dd + 1]);
      }
    }
    for (int k = 0; k < 8; ++k)
      wsu[WS_WI0 + k * 512 + j] = pk16(Wih0[j * 16 + 2 * k], Wih0[j * 16 + 2 * k + 1]);
    ws[WS_BS0 + j] = bih0[j] + bhh0[j];
    ws[WS_BS1 + j] = bih1[j] + bhh1[j];
  }
  for (int e = tid; e < ZD * ZD; e += nt) {
    int i = e >> 5, j = e & 31;
    float s = 0.f;
    for (int k = 0; k < ZD; ++k) s += QL[i * ZD + k] * QL[j * ZD + k];
    if (i == j) s += 0.001f;
    ws[WS_Q + e] = s;
  }
  for (int e = tid; e < AD * AD; e += nt) {
    int i = e >> 4, j = e & 15;
    float s = 0.f;
    for (int k = 0; k < AD; ++k) s += RL[i * AD + k] * RL[j * AD + k];
    if (i == j) s += 0.001f;
    ws[WS_R + e] = s;
  }
}

__device__ __forceinline__ float sigm(float x) { return 1.0f / (1.0f + expf(-x)); }
__device__ __forceinline__ float dotv(f32x4 a, f32x4 b) {
  return a[0] * b[0] + a[1] * b[1] + a[2] * b[2] + a[3] * b[3];
}
__device__ __forceinline__ void st_nt(float* p, float v) { __builtin_nontemporal_store(v, p); }
__device__ __forceinline__ void st_nt4(float* p, f32x4 v) {
  __builtin_nontemporal_store(v, (f32x4*)p);
}

__device__ __forceinline__ float dot2f(unsigned a, unsigned b, float c) {
#if __has_builtin(__builtin_amdgcn_fdot2)
  typedef _Float16 h2 __attribute__((ext_vector_type(2)));
  union U { unsigned u; h2 h; };
  U ua, ub; ua.u = a; ub.u = b;
  return __builtin_amdgcn_fdot2(ua.h, ub.h, c, false);
#else
  union U { unsigned u; _Float16 h[2]; };
  U ua, ub; ua.u = a; ub.u = b;
  return c + (float)ua.h[0] * (float)ub.h[0] + (float)ua.h[1] * (float)ub.h[1];
#endif
}

// ============================ Kernel 1: LSTM chain (GPB=1, round-14 proven) ============================
struct alignas(16) LS {
  unsigned ap[8];
  unsigned h0p[64];
  unsigned h1p[64];
  float g[G4H];
  float lgp[16];
};

__global__ void __launch_bounds__(NTHR, 2) ssm_lstm_kernel(
    const float* __restrict__ as_, const float* __restrict__ AK, const float* __restrict__ CK,
    const float* __restrict__ Wout, const float* __restrict__ bout,
    const float* __restrict__ ws, float* __restrict__ out) {
  __shared__ LS s;
  const int tid = threadIdx.x;
  const int b = blockIdx.x;
  const unsigned* wsu = (const unsigned*)ws;
  const uint4* Wg = (const uint4*)(wsu + WS_WQ);
  const f32x4* AK4 = (const f32x4*)AK;
  const f32x4* CK4 = (const f32x4*)CK;

  float* o_As = out + (size_t)T_STEPS * B_SZ * ZD + (size_t)T_STEPS * B_SZ * ZD * ZD +
                (size_t)T_STEPS * B_SZ * ZD + (size_t)T_STEPS * B_SZ * ZD * ZD;
  float* o_Cs = o_As + (size_t)(T_STEPS + 1) * B_SZ * ZD * ZD;
  float* o_a = o_Cs + (size_t)(T_STEPS + 1) * B_SZ * AD * ZD;

  const uint4* h0p4 = (const uint4*)s.h0p;
  const uint4* h1p4 = (const uint4*)s.h1p;
  const uint4* ap4 = (const uint4*)s.ap;

  unsigned wi0r[8];
  #pragma unroll
  for (int k = 0; k < 8; ++k) wi0r[k] = wsu[WS_WI0 + k * 512 + tid];
  const float bs0r = ws[WS_BS0 + tid];
  const float bs1r = ws[WS_BS1 + tid];
  float woutr[8];
  #pragma unroll
  for (int gi = 0; gi < KM; ++gi) woutr[gi] = (tid < HID) ? Wout[gi * HID + tid] : 0.f;
  float boutr[8];
  #pragma unroll
  for (int k = 0; k < KM; ++k) boutr[k] = bout[k];

  float c0r = 0.f, c1r = 0.f;

  if (tid < 64) { s.h0p[tid] = 0u; s.h1p[tid] = 0u; }
  if (tid < AD) {
    float v = as_[(size_t)b * AD + tid];
    ((__half*)s.ap)[tid] = __float2half_rn(v);
    st_nt(&o_a[(size_t)b * AD + tid], v);
  }
  if (tid < 256) {
    f32x4 acc = {0.f, 0.f, 0.f, 0.f};
    #pragma unroll
    for (int k = 0; k < KM; ++k) acc += AK4[k * 256 + tid];
    st_nt4(&o_As[(size_t)b * 1024 + tid * 4], acc);
  } else if (tid < 384) {
    int idx = tid - 256;
    f32x4 acc = {0.f, 0.f, 0.f, 0.f};
    #pragma unroll
    for (int k = 0; k < KM; ++k) acc += CK4[k * 128 + idx];
    st_nt4(&o_Cs[(size_t)b * 512 + idx * 4], acc);
  }
  __syncthreads();

  for (int t = 0; t < T_STEPS; ++t) {
    const size_t tb2 = (size_t)(t + 1) * B_SZ + b;

    {  // A: L0 gates (stream W_hh0)
      float acc = bs0r;
      #pragma unroll
      for (int k4 = 0; k4 < 2; ++k4) {
        uint4 av = ap4[k4];
        acc = dot2f(av.x, wi0r[k4 * 4 + 0], acc);
        acc = dot2f(av.y, wi0r[k4 * 4 + 1], acc);
        acc = dot2f(av.z, wi0r[k4 * 4 + 2], acc);
        acc = dot2f(av.w, wi0r[k4 * 4 + 3], acc);
      }
      #pragma unroll
      for (int d4 = 0; d4 < 16; ++d4) {
        uint4 w = Wg[d4 * 512 + tid];
        uint4 hv = h0p4[d4];
        acc = dot2f(hv.x, w.x, acc);
        acc = dot2f(hv.y, w.y, acc);
        acc = dot2f(hv.z, w.z, acc);
        acc = dot2f(hv.w, w.w, acc);
      }
      s.g[tid] = acc;
    }
    __syncthreads();

    if (tid < HID) {  // B: h0/c0
      float ig = sigm(s.g[tid]);
      float fg = sigm(s.g[HID + tid]);
      float gg = tanhf(s.g[2 * HID + tid]);
      float og = sigm(s.g[3 * HID + tid]);
      c0r = fg * c0r + ig * gg;
      ((__half*)s.h0p)[tid] = __float2half_rn(og * tanhf(c0r));
    }
    __syncthreads();

    {  // C: L1 gates (stream W_ih1 + W_hh1)
      float acc = bs1r;
      #pragma unroll
      for (int d4 = 0; d4 < 16; ++d4) {
        uint4 w = Wg[(16 + d4) * 512 + tid];
        uint4 hv = h0p4[d4];
        acc = dot2f(hv.x, w.x, acc);
        acc = dot2f(hv.y, w.y, acc);
        acc = dot2f(hv.z, w.z, acc);
        acc = dot2f(hv.w, w.w, acc);
      }
      #pragma unroll
      for (int d4 = 0; d4 < 16; ++d4) {
        uint4 w = Wg[(32 + d4) * 512 + tid];
        uint4 hv = h1p4[d4];
        acc = dot2f(hv.x, w.x, acc);
        acc = dot2f(hv.y, w.y, acc);
        acc = dot2f(hv.z, w.z, acc);
        acc = dot2f(hv.w, w.w, acc);
      }
      s.g[tid] = acc;
    }
    __syncthreads();

    if (tid < HID) {  // D: h1/c1 + logit partials
      float ig = sigm(s.g[tid]);
      float fg = sigm(s.g[HID + tid]);
      float gg = tanhf(s.g[2 * HID + tid]);
      float og = sigm(s.g[3 * HID + tid]);
      c1r = fg * c1r + ig * gg;
      float h1u = og * tanhf(c1r);
      ((__half*)s.h1p)[tid] = __float2half_rn(h1u);
      int w2 = tid >> 6, lane = tid & 63;
      #pragma unroll
      for (int gi = 0; gi < KM; ++gi) {
        float p = woutr[gi] * h1u;
        #pragma unroll
        for (int m = 32; m >= 1; m >>= 1) p += __shfl_xor(p, m);
        if (lane == 0) s.lgp[w2 * KM + gi] = p;
      }
    }
    __syncthreads();

    {  // E: softmax + einsum outputs + a prefetch
      float lg[KM];
      float mx = -1e30f;
      #pragma unroll
      for (int k = 0; k < KM; ++k) {
        lg[k] = s.lgp[k] + s.lgp[KM + k] + boutr[k];
        mx = fmaxf(mx, lg[k]);
      }
      float sum = 0.f;
      #pragma unroll
      for (int k = 0; k < KM; ++k) { lg[k] = expf(lg[k] - mx); sum += lg[k]; }
      float inv = 1.0f / sum;
      #pragma unroll
      for (int k = 0; k < KM; ++k) lg[k] *= inv;
      if (tid < 256) {
        f32x4 acc = {0.f, 0.f, 0.f, 0.f};
        #pragma unroll
        for (int k = 0; k < KM; ++k) acc += lg[k] * AK4[k * 256 + tid];
        st_nt4(&o_As[tb2 * 1024 + tid * 4], acc);
      } else if (tid < 384) {
        int idx = tid - 256;
        f32x4 acc = {0.f, 0.f, 0.f, 0.f};
        #pragma unroll
        for (int k = 0; k < KM; ++k) acc += lg[k] * CK4[k * 128 + idx];
        st_nt4(&o_Cs[tb2 * 512 + idx * 4], acc);
      } else if (tid >= 448 && tid < 448 + AD && t < T_STEPS - 1) {
        int i = tid - 448;
        float v = as_[tb2 * AD + i];
        ((__half*)s.ap)[i] = __float2half_rn(v);
        st_nt(&o_a[tb2 * AD + i], v);
      }
    }
    __syncthreads();
  }
}

// ===== Kernel 2: Kalman — round-17 version verbatim: 4 waves/batch, separate Sy
// ===== phase, all global stores deferred to one drain in the final phase.
struct alignas(16) KS {
  float P[ZD * 36];
  float An[ZD * 36];
  float Mt[ZD * 36];
  float MtT[ZD * 36];
  float Sy[ZD * 36];
  float ACt[ZD * 36];
  float Qs[ZD * 36];
  float C[AD * 36];
  float Aug[AD * 52];
  float Kk[ZD * 20];
  float Rs[AD * AD];
  float meanp[ZD], meant[ZD], r[AD], af[AD];
};

__global__ void __launch_bounds__(256, 1) ssm_kalman_kernel(
    const float* __restrict__ as_, const float* __restrict__ initm,
    const float* __restrict__ initc, const float* __restrict__ ws,
    float* __restrict__ out) {
  __shared__ KS s;
  const int l = threadIdx.x;
  const int b = blockIdx.x;
  const int i32 = l & 31, cq = l >> 5;
  const int i16 = l & 15, j16 = l >> 4;

  float* o_means = out;
  float* o_covs = o_means + (size_t)T_STEPS * B_SZ * ZD;
  float* o_nmean = o_covs + (size_t)T_STEPS * B_SZ * ZD * ZD;
  float* o_ncovs = o_nmean + (size_t)T_STEPS * B_SZ * ZD;
  const float* o_As = o_ncovs + (size_t)T_STEPS * B_SZ * ZD * ZD;
  const float* o_Cs = o_As + (size_t)(T_STEPS + 1) * B_SZ * ZD * ZD;

  f32x4* P4 = (f32x4*)s.P;
  f32x4* An4 = (f32x4*)s.An;
  f32x4* Mt4 = (f32x4*)s.Mt;
  f32x4* MtT4 = (f32x4*)s.MtT;
  f32x4* Sy4 = (f32x4*)s.Sy;
  f32x4* ACt4 = (f32x4*)s.ACt;
  f32x4* Q4 = (f32x4*)s.Qs;
  f32x4* C4 = (f32x4*)s.C;
  f32x4* Aug4 = (f32x4*)s.Aug;
  f32x4* Kk4 = (f32x4*)s.Kk;
  f32x4* af4 = (f32x4*)s.af;
  const f32x4* r4 = (const f32x4*)s.r;
  const f32x4* meanp4 = (const f32x4*)s.meanp;
  const f32x4* meant4 = (const f32x4*)s.meant;

  #pragma unroll
  for (int q = 0; q < 4; ++q) {
    int e = q * 256 + l;
    s.P[(e >> 5) * 36 + (e & 31)] = initc[e];
    s.Qs[(e >> 5) * 36 + (e & 31)] = ws[WS_Q + e];
  }
  s.Rs[l] = ws[WS_R + l];
  if (l < ZD) s.meanp[l] = initm[l];
  {
    const f32x4* gc = (const f32x4*)&o_Cs[(size_t)b * 512];
    if (l < 128) C4[(l >> 3) * 9 + (l & 7)] = gc[l];
    const f32x4* ga = (const f32x4*)&o_As[((size_t)B_SZ + b) * 1024];
    An4[(l >> 3) * 9 + (l & 7)] = ga[l];
    if (l < 4) af4[l] = ((const f32x4*)&as_[(size_t)b * AD])[l];
  }
  __syncthreads();

  for (int t = 0; t < T_STEPS; ++t) {
    const size_t tb = (size_t)t * B_SZ + b;
    const bool pf = (t < T_STEPS - 1);

    // P0: issue prefetch (registers; C committed in P3, An/a in P8)
    f32x4 pfC = {0, 0, 0, 0};
    f32x4 pfA = {0, 0, 0, 0};
    f32x4 pfa = {0, 0, 0, 0};
    if (pf) {
      if (l >= 128) pfC = ((const f32x4*)&o_Cs[(tb + B_SZ) * 512])[l - 128];
      pfA = ((const f32x4*)&o_As[(tb + 2 * B_SZ) * 1024])[l];
      if (l < 4) pfa = ((const f32x4*)&as_[(tb + B_SZ) * AD])[l];
    }

    // deferred-store registers (carried across barriers; stored in P8)
    float meant_r = 0.f, nmean_r = 0.f;
    f32x4 covs_r = {0, 0, 0, 0};

    // P1: CP = C @ P -> Aug right half
    {
      float a0 = 0.f, a1 = 0.f;
      #pragma unroll
      for (int k4 = 0; k4 < 8; ++k4) {
        f32x4 cr = C4[i16 * 9 + k4];
        a0 += dotv(cr, P4[j16 * 9 + k4]);
        a1 += dotv(cr, P4[(j16 + 16) * 9 + k4]);
      }
      s.Aug[i16 * 52 + AD + j16] = a0;
      s.Aug[i16 * 52 + AD + j16 + 16] = a1;
    }
    __syncthreads();

    // P2: S = CP C^T + R -> Aug left; r
    {
      float acc = s.Rs[i16 * AD + j16];
      #pragma unroll
      for (int k4 = 0; k4 < 8; ++k4)
        acc += dotv(Aug4[i16 * 13 + 4 + k4], C4[j16 * 9 + k4]);
      s.Aug[i16 * 52 + j16] = acc;
      if (l >= 240) {
        int ii = l - 240;
        float rr = s.af[ii];
        #pragma unroll
        for (int k4 = 0; k4 < 8; ++k4) rr -= dotv(C4[ii * 9 + k4], meanp4[k4]);
        s.r[ii] = rr;
      }
    }
    __syncthreads();

    // P3: wave 0 GJ -> K  |  threads 128..255 commit prefetched C
    if (l < 64) {
      const int lc = (l < 48) ? l : 47;
      float col[16];
      #pragma unroll
      for (int i = 0; i < AD; ++i) col[i] = s.Aug[i * 52 + lc];
      #pragma unroll
      for (int j = 0; j < AD; ++j) {
        float pd = __shfl(col[j], j);
        float pinv = 1.0f / pd;
        float oldj = col[j];
        #pragma unroll
        for (int i = 0; i < AD; ++i) {
          if (i == j) continue;
          float fi = __shfl(col[i], j);
          col[i] = fmaf(-(fi * pinv), oldj, col[i]);
        }
        col[j] = oldj * pinv;
      }
      if (l >= AD && l < AD + ZD) {
        int rr = l - AD;
        f32x4 v0 = {col[0], col[1], col[2], col[3]};
        f32x4 v1 = {col[4], col[5], col[6], col[7]};
        f32x4 v2 = {col[8], col[9], col[10], col[11]};
        f32x4 v3 = {col[12], col[13], col[14], col[15]};
        Kk4[rr * 5 + 0] = v0;
        Kk4[rr * 5 + 1] = v1;
        Kk4[rr * 5 + 2] = v2;
        Kk4[rr * 5 + 3] = v3;
      }
    } else if (pf && l >= 128) {
      int idx = l - 128;
      C4[(idx >> 3) * 9 + (idx & 7)] = pfC;
    }
    __syncthreads();

    // P4: cov_t = P - K@CP -> Mt, MtT
    {
      f32x4 acc = {0.f, 0.f, 0.f, 0.f};
      #pragma unroll
      for (int k4 = 0; k4 < 4; ++k4) {
        f32x4 kv = Kk4[i32 * 5 + k4];
        #pragma unroll
        for (int kk = 0; kk < 4; ++kk) {
          f32x4 cpk = Aug4[(4 * k4 + kk) * 13 + 4 + cq];
          acc += kv[kk] * cpk;
        }
      }
      f32x4 mv = P4[i32 * 9 + cq] - acc;
      Mt4[i32 * 9 + cq] = mv;
      #pragma unroll
      for (int jj = 0; jj < 4; ++jj) s.MtT[(4 * cq + jj) * 36 + i32] = mv[jj];
    }
    __syncthreads();

    // P5: Sy = 0.5(Mt+MtT) (reg-kept for store); mean_t (reg-kept)
    {
      covs_r = 0.5f * (Mt4[i32 * 9 + cq] + MtT4[i32 * 9 + cq]);
      Sy4[i32 * 9 + cq] = covs_r;
      if (l < ZD) {
        float acc = s.meanp[l];
        #pragma unroll
        for (int m = 0; m < 4; ++m) acc += dotv(Kk4[l * 5 + m], r4[m]);
        s.meant[l] = acc;
        meant_r = acc;
      }
    }
    __syncthreads();

    // P6: ACt = An @ Sy
    {
      float c0 = 0.f, c1 = 0.f, c2 = 0.f, c3 = 0.f;
      #pragma unroll
      for (int k4 = 0; k4 < 8; ++k4) {
        f32x4 an = An4[i32 * 9 + k4];
        c0 += dotv(an, Sy4[(4 * cq + 0) * 9 + k4]);
        c1 += dotv(an, Sy4[(4 * cq + 1) * 9 + k4]);
        c2 += dotv(an, Sy4[(4 * cq + 2) * 9 + k4]);
        c3 += dotv(an, Sy4[(4 * cq + 3) * 9 + k4]);
      }
      f32x4 v = {c0, c1, c2, c3};
      ACt4[i32 * 9 + cq] = v;
    }
    __syncthreads();

    // P7: M2 = ACt @ An^T -> Mt/MtT; meanp' (reg-kept)
    {
      if (l < ZD) {
        float acc = 0.f;
        #pragma unroll
        for (int k4 = 0; k4 < 8; ++k4) acc += dotv(An4[l * 9 + k4], meant4[k4]);
        s.meanp[l] = acc;
        nmean_r = acc;
      }
      float c0 = 0.f, c1 = 0.f, c2 = 0.f, c3 = 0.f;
      #pragma unroll
      for (int k4 = 0; k4 < 8; ++k4) {
        f32x4 ac = ACt4[i32 * 9 + k4];
        c0 += dotv(ac, An4[(4 * cq + 0) * 9 + k4]);
        c1 += dotv(ac, An4[(4 * cq + 1) * 9 + k4]);
        c2 += dotv(ac, An4[(4 * cq + 2) * 9 + k4]);
        c3 += dotv(ac, An4[(4 * cq + 3) * 9 + k4]);
      }
      f32x4 mv = {c0, c1, c2, c3};
      Mt4[i32 * 9 + cq] = mv;
      #pragma unroll
      for (int jj = 0; jj < 4; ++jj) s.MtT[(4 * cq + jj) * 36 + i32] = mv[jj];
    }
    __syncthreads();

    // P8: P' = 0.5(M2+M2^T) + Q -> P; THEN all global stores (single drain);
    //     commit prefetched An/a.
    {
      f32x4 pv = 0.5f * (Mt4[i32 * 9 + cq] + MtT4[i32 * 9 + cq]) + Q4[i32 * 9 + cq];
      P4[i32 * 9 + cq] = pv;
      st_nt4(&o_ncovs[tb * 1024 + i32 * 32 + cq * 4], pv);
      st_nt4(&o_covs[tb * 1024 + i32 * 32 + cq * 4], covs_r);
      if (l < ZD) {
        st_nt(&o_means[tb * ZD + l], meant_r);
        st_nt(&o_nmean[tb * ZD + l], nmean_r);
      }
      if (pf) {
        An4[(l >> 3) * 9 + (l & 7)] = pfA;
        if (l < 4) af4[l] = pfa;
      }
    }
    __syncthreads();
  }
}

extern "C" void kernel_launch(void* const* d_in, const int* in_sizes, int n_in,
                              void* d_out, int out_size, void* d_ws, size_t ws_size,
                              hipStream_t stream) {
  const float* as_ = (const float*)d_in[0];
  const float* AK = (const float*)d_in[1];
  const float* CK = (const float*)d_in[2];
  const float* QL = (const float*)d_in[3];
  const float* RL = (const float*)d_in[4];
  const float* initm = (const float*)d_in[5];
  const float* initc = (const float*)d_in[6];
  const float* Wih0 = (const float*)d_in[7];
  const float* Whh0 = (const float*)d_in[8];
  const float* bih0 = (const float*)d_in[9];
  const float* bhh0 = (const float*)d_in[10];
  const float* Wih1 = (const float*)d_in[11];
  const float* Whh1 = (const float*)d_in[12];
  const float* bih1 = (const float*)d_in[13];
  const float* bhh1 = (const float*)d_in[14];
  const float* Wout = (const float*)d_in[15];
  const float* bout = (const float*)d_in[16];
  float* ws = (float*)d_ws;
  float* out = (float*)d_out;

  ssm_prep_kernel<<<16, 256, 0, stream>>>(Wih0, Whh0, Wih1, Whh1, bih0, bhh0, bih1, bhh1,
                                          QL, RL, ws);
  ssm_lstm_kernel<<<B_SZ, NTHR, 0, stream>>>(as_, AK, CK, Wout, bout, ws, out);
  ssm_kalman_kernel<<<B_SZ, 256, 0, stream>>>(as_, initm, initc, ws, out);
}

// Round 20
// 1588.659 us; speedup vs baseline: 3.6294x; 1.0248x over previous
//
#include <hip/hip_runtime.h>
#include <hip/hip_fp16.h>
#include <math.h>

#define T_STEPS 128
#define B_SZ 256
#define AD 16
#define ZD 32
#define KM 8
#define HID 128
#define G4H 512
#define NTHR 512

// ws layout (4-byte word offsets)
#define WS_WQ   0
#define WS_WI0  98304
#define WS_BS0  102400
#define WS_BS1  102912
#define WS_Q    103424
#define WS_R    104448

typedef float f32x4 __attribute__((ext_vector_type(4)));

__device__ __forceinline__ unsigned pk16(float lo, float hi) {
  unsigned a = __half_as_ushort(__float2half_rn(lo));
  unsigned b = __half_as_ushort(__float2half_rn(hi));
  return a | (b << 16);
}

__global__ void ssm_prep_kernel(const float* __restrict__ Wih0, const float* __restrict__ Whh0,
                                const float* __restrict__ Wih1, const float* __restrict__ Whh1,
                                const float* __restrict__ bih0, const float* __restrict__ bhh0,
                                const float* __restrict__ bih1, const float* __restrict__ bhh1,
                                const float* __restrict__ QL, const float* __restrict__ RL,
                                float* __restrict__ ws) {
  unsigned* wsu = (unsigned*)ws;
  int tid = blockIdx.x * blockDim.x + threadIdx.x;
  int nt = gridDim.x * blockDim.x;
  for (int j = tid; j < G4H; j += nt) {
    for (int d4 = 0; d4 < 48; ++d4) {
      for (int m = 0; m < 4; ++m) {
        int dd = (d4 & 15) * 4 + m;
        const float* src = (d4 < 16) ? Whh0 : (d4 < 32) ? Wih1 : Whh1;
        wsu[WS_WQ + (d4 * 512 + j) * 4 + m] =
            pk16(src[j * 128 + 2 * dd], src[j * 128 + 2 * dd + 1]);
      }
    }
    for (int k = 0; k < 8; ++k)
      wsu[WS_WI0 + k * 512 + j] = pk16(Wih0[j * 16 + 2 * k], Wih0[j * 16 + 2 * k + 1]);
    ws[WS_BS0 + j] = bih0[j] + bhh0[j];
    ws[WS_BS1 + j] = bih1[j] + bhh1[j];
  }
  for (int e = tid; e < ZD * ZD; e += nt) {
    int i = e >> 5, j = e & 31;
    float s = 0.f;
    for (int k = 0; k < ZD; ++k) s += QL[i * ZD + k] * QL[j * ZD + k];
    if (i == j) s += 0.001f;
    ws[WS_Q + e] = s;
  }
  for (int e = tid; e < AD * AD; e += nt) {
    int i = e >> 4, j = e & 15;
    float s = 0.f;
    for (int k = 0; k < AD; ++k) s += RL[i * AD + k] * RL[j * AD + k];
    if (i == j) s += 0.001f;
    ws[WS_R + e] = s;
  }
}

__device__ __forceinline__ float sigm(float x) { return 1.0f / (1.0f + expf(-x)); }
__device__ __forceinline__ float dotv(f32x4 a, f32x4 b) {
  return a[0] * b[0] + a[1] * b[1] + a[2] * b[2] + a[3] * b[3];
}
__device__ __forceinline__ void st_nt(float* p, float v) { __builtin_nontemporal_store(v, p); }
__device__ __forceinline__ void st_nt4(float* p, f32x4 v) {
  __builtin_nontemporal_store(v, (f32x4*)p);
}

__device__ __forceinline__ float dot2f(unsigned a, unsigned b, float c) {
#if __has_builtin(__builtin_amdgcn_fdot2)
  typedef _Float16 h2 __attribute__((ext_vector_type(2)));
  union U { unsigned u; h2 h; };
  U ua, ub; ua.u = a; ub.u = b;
  return __builtin_amdgcn_fdot2(ua.h, ub.h, c, false);
#else
  union U { unsigned u; _Float16 h[2]; };
  U ua, ub; ua.u = a; ub.u = b;
  return c + (float)ua.h[0] * (float)ub.h[0] + (float)ua.h[1] * (float)ub.h[1];
#endif
}

// ============================ Kernel 1: LSTM chain ============================
struct alignas(16) LS {
  unsigned ap[8];
  unsigned h0p[64];
  unsigned h1p[64];
  float g[G4H];
  float lgp[16];
};

__global__ void __launch_bounds__(NTHR, 2) ssm_lstm_kernel(
    const float* __restrict__ as_, const float* __restrict__ AK, const float* __restrict__ CK,
    const float* __restrict__ Wout, const float* __restrict__ bout,
    const float* __restrict__ ws, float* __restrict__ out) {
  __shared__ LS s;
  const int tid = threadIdx.x;
  const int b = blockIdx.x;
  const unsigned* wsu = (const unsigned*)ws;
  const uint4* Wg = (const uint4*)(wsu + WS_WQ);
  const f32x4* AK4 = (const f32x4*)AK;
  const f32x4* CK4 = (const f32x4*)CK;

  float* o_As = out + (size_t)T_STEPS * B_SZ * ZD + (size_t)T_STEPS * B_SZ * ZD * ZD +
                (size_t)T_STEPS * B_SZ * ZD + (size_t)T_STEPS * B_SZ * ZD * ZD;
  float* o_Cs = o_As + (size_t)(T_STEPS + 1) * B_SZ * ZD * ZD;
  float* o_a = o_Cs + (size_t)(T_STEPS + 1) * B_SZ * AD * ZD;

  const uint4* h0p4 = (const uint4*)s.h0p;
  const uint4* h1p4 = (const uint4*)s.h1p;
  const uint4* ap4 = (const uint4*)s.ap;

  unsigned wi0r[8];
  #pragma unroll
  for (int k = 0; k < 8; ++k) wi0r[k] = wsu[WS_WI0 + k * 512 + tid];
  const float bs0r = ws[WS_BS0 + tid];
  const float bs1r = ws[WS_BS1 + tid];
  float woutr[8];
  #pragma unroll
  for (int gi = 0; gi < KM; ++gi) woutr[gi] = (tid < HID) ? Wout[gi * HID + tid] : 0.f;
  float boutr[8];
  #pragma unroll
  for (int k = 0; k < KM; ++k) boutr[k] = bout[k];

  float c0r = 0.f, c1r = 0.f;

  if (tid < 64) { s.h0p[tid] = 0u; s.h1p[tid] = 0u; }
  if (tid < AD) {
    float v = as_[(size_t)b * AD + tid];
    ((__half*)s.ap)[tid] = __float2half_rn(v);
    st_nt(&o_a[(size_t)b * AD + tid], v);
  }
  if (tid < 256) {
    f32x4 acc = {0.f, 0.f, 0.f, 0.f};
    #pragma unroll
    for (int k = 0; k < KM; ++k) acc += AK4[k * 256 + tid];
    st_nt4(&o_As[(size_t)b * 1024 + tid * 4], acc);
  } else if (tid < 384) {
    int idx = tid - 256;
    f32x4 acc = {0.f, 0.f, 0.f, 0.f};
    #pragma unroll
    for (int k = 0; k < KM; ++k) acc += CK4[k * 128 + idx];
    st_nt4(&o_Cs[(size_t)b * 512 + idx * 4], acc);
  }
  __syncthreads();

  for (int t = 0; t < T_STEPS; ++t) {
    const size_t tb2 = (size_t)(t + 1) * B_SZ + b;

    // A: L0 gates (stream W_hh0)
    {
      float acc = bs0r;
      #pragma unroll
      for (int k4 = 0; k4 < 2; ++k4) {
        uint4 av = ap4[k4];
        acc = dot2f(av.x, wi0r[k4 * 4 + 0], acc);
        acc = dot2f(av.y, wi0r[k4 * 4 + 1], acc);
        acc = dot2f(av.z, wi0r[k4 * 4 + 2], acc);
        acc = dot2f(av.w, wi0r[k4 * 4 + 3], acc);
      }
      #pragma unroll
      for (int d4 = 0; d4 < 16; ++d4) {
        uint4 w = Wg[d4 * 512 + tid];
        uint4 hv = h0p4[d4];
        acc = dot2f(hv.x, w.x, acc);
        acc = dot2f(hv.y, w.y, acc);
        acc = dot2f(hv.z, w.z, acc);
        acc = dot2f(hv.w, w.w, acc);
      }
      s.g[tid] = acc;
    }
    __syncthreads();

    // B: h0/c0
    if (tid < HID) {
      float ig = sigm(s.g[tid]);
      float fg = sigm(s.g[HID + tid]);
      float gg = tanhf(s.g[2 * HID + tid]);
      float og = sigm(s.g[3 * HID + tid]);
      c0r = fg * c0r + ig * gg;
      ((__half*)s.h0p)[tid] = __float2half_rn(og * tanhf(c0r));
    }
    __syncthreads();

    // C: L1 gates (stream W_ih1 + W_hh1)
    {
      float acc = bs1r;
      #pragma unroll
      for (int d4 = 0; d4 < 16; ++d4) {
        uint4 w = Wg[(16 + d4) * 512 + tid];
        uint4 hv = h0p4[d4];
        acc = dot2f(hv.x, w.x, acc);
        acc = dot2f(hv.y, w.y, acc);
        acc = dot2f(hv.z, w.z, acc);
        acc = dot2f(hv.w, w.w, acc);
      }
      #pragma unroll
      for (int d4 = 0; d4 < 16; ++d4) {
        uint4 w = Wg[(32 + d4) * 512 + tid];
        uint4 hv = h1p4[d4];
        acc = dot2f(hv.x, w.x, acc);
        acc = dot2f(hv.y, w.y, acc);
        acc = dot2f(hv.z, w.z, acc);
        acc = dot2f(hv.w, w.w, acc);
      }
      s.g[tid] = acc;
    }
    __syncthreads();

    // D: h1/c1 + logit partials
    if (tid < HID) {
      float ig = sigm(s.g[tid]);
      float fg = sigm(s.g[HID + tid]);
      float gg = tanhf(s.g[2 * HID + tid]);
      float og = sigm(s.g[3 * HID + tid]);
      c1r = fg * c1r + ig * gg;
      float h1u = og * tanhf(c1r);
      ((__half*)s.h1p)[tid] = __float2half_rn(h1u);
      int w2 = tid >> 6, lane = tid & 63;
      #pragma unroll
      for (int gi = 0; gi < KM; ++gi) {
        float p = woutr[gi] * h1u;
        #pragma unroll
        for (int m = 32; m >= 1; m >>= 1) p += __shfl_xor(p, m);
        if (lane == 0) s.lgp[w2 * KM + gi] = p;
      }
    }
    __syncthreads();

    // E: softmax + einsum outputs + a prefetch
    {
      float lg[KM];
      float mx = -1e30f;
      #pragma unroll
      for (int k = 0; k < KM; ++k) {
        lg[k] = s.lgp[k] + s.lgp[KM + k] + boutr[k];
        mx = fmaxf(mx, lg[k]);
      }
      float sum = 0.f;
      #pragma unroll
      for (int k = 0; k < KM; ++k) { lg[k] = expf(lg[k] - mx); sum += lg[k]; }
      float inv = 1.0f / sum;
      #pragma unroll
      for (int k = 0; k < KM; ++k) lg[k] *= inv;
      if (tid < 256) {
        f32x4 acc = {0.f, 0.f, 0.f, 0.f};
        #pragma unroll
        for (int k = 0; k < KM; ++k) acc += lg[k] * AK4[k * 256 + tid];
        st_nt4(&o_As[tb2 * 1024 + tid * 4], acc);
      } else if (tid < 384) {
        int idx = tid - 256;
        f32x4 acc = {0.f, 0.f, 0.f, 0.f};
        #pragma unroll
        for (int k = 0; k < KM; ++k) acc += lg[k] * CK4[k * 128 + idx];
        st_nt4(&o_Cs[tb2 * 512 + idx * 4], acc);
      } else if (tid >= 448 && tid < 448 + AD && t < T_STEPS - 1) {
        int i = tid - 448;
        float v = as_[tb2 * AD + i];
        ((__half*)s.ap)[i] = __float2half_rn(v);
        st_nt(&o_a[tb2 * AD + i], v);
      }
    }
    __syncthreads();
  }
}

// ===== Kernel 2: Kalman chain — 4 waves/batch (256 thr), GJ on wave 0, prefetched =====
struct alignas(16) KS {
  float P[ZD * 36];
  float An[ZD * 36];
  float Mt[ZD * 36];
  float MtT[ZD * 36];
  float Sy[ZD * 36];
  float ACt[ZD * 36];
  float Qs[ZD * 36];
  float C[AD * 36];
  float Aug[AD * 52];    // [S(16) | CP(32)] per row
  float Kk[ZD * 20];
  float Rs[AD * AD];
  float meanp[ZD], meant[ZD], r[AD], af[AD];
};

__global__ void __launch_bounds__(256, 1) ssm_kalman_kernel(
    const float* __restrict__ as_, const float* __restrict__ initm,
    const float* __restrict__ initc, const float* __restrict__ ws,
    float* __restrict__ out) {
  __shared__ KS s;
  const int l = threadIdx.x;           // 0..255
  const int b = blockIdx.x;
  const int i32 = l & 31, cq = l >> 5; // 32-row f32x4 phases (2-way-max banks)
  const int i16 = l & 15, j16 = l >> 4;// 16-row phases

  float* o_means = out;
  float* o_covs = o_means + (size_t)T_STEPS * B_SZ * ZD;
  float* o_nmean = o_covs + (size_t)T_STEPS * B_SZ * ZD * ZD;
  float* o_ncovs = o_nmean + (size_t)T_STEPS * B_SZ * ZD;
  const float* o_As = o_ncovs + (size_t)T_STEPS * B_SZ * ZD * ZD;
  const float* o_Cs = o_As + (size_t)(T_STEPS + 1) * B_SZ * ZD * ZD;

  f32x4* P4 = (f32x4*)s.P;        // stride 9
  f32x4* An4 = (f32x4*)s.An;
  f32x4* Mt4 = (f32x4*)s.Mt;
  f32x4* MtT4 = (f32x4*)s.MtT;
  f32x4* Sy4 = (f32x4*)s.Sy;
  f32x4* ACt4 = (f32x4*)s.ACt;
  f32x4* Q4 = (f32x4*)s.Qs;
  f32x4* C4 = (f32x4*)s.C;
  f32x4* Aug4 = (f32x4*)s.Aug;    // stride 13; CP at +4
  f32x4* Kk4 = (f32x4*)s.Kk;      // stride 5
  f32x4* af4 = (f32x4*)s.af;
  const f32x4* r4 = (const f32x4*)s.r;
  const f32x4* meanp4 = (const f32x4*)s.meanp;
  const f32x4* meant4 = (const f32x4*)s.meant;

  // ---- init ----
  #pragma unroll
  for (int q = 0; q < 4; ++q) {
    int e = q * 256 + l;
    s.P[(e >> 5) * 36 + (e & 31)] = initc[e];
    s.Qs[(e >> 5) * 36 + (e & 31)] = ws[WS_Q + e];
  }
  s.Rs[l] = ws[WS_R + l];
  if (l < ZD) s.meanp[l] = initm[l];
  {
    const f32x4* gc = (const f32x4*)&o_Cs[(size_t)b * 512];
    if (l < 128) C4[(l >> 3) * 9 + (l & 7)] = gc[l];
    const f32x4* ga = (const f32x4*)&o_As[((size_t)B_SZ + b) * 1024];
    An4[(l >> 3) * 9 + (l & 7)] = ga[l];
    if (l < 4) af4[l] = ((const f32x4*)&as_[(size_t)b * AD])[l];
  }
  __syncthreads();

  for (int t = 0; t < T_STEPS; ++t) {
    const size_t tb = (size_t)t * B_SZ + b;
    const bool pf = (t < T_STEPS - 1);

    // P0: issue prefetch for step t+1 (registers; C on threads >=128, An on all)
    f32x4 pfC = {0, 0, 0, 0};
    f32x4 pfA = {0, 0, 0, 0};
    f32x4 pfa = {0, 0, 0, 0};
    if (pf) {
      if (l >= 128) pfC = ((const f32x4*)&o_Cs[(tb + B_SZ) * 512])[l - 128];
      pfA = ((const f32x4*)&o_As[(tb + 2 * B_SZ) * 1024])[l];
      if (l < 4) pfa = ((const f32x4*)&as_[(tb + B_SZ) * AD])[l];
    }

    // P1: CP = C @ P (P symmetric -> row dots) -> Aug right half (2 outputs/thread)
    {
      float a0 = 0.f, a1 = 0.f;
      #pragma unroll
      for (int k4 = 0; k4 < 8; ++k4) {
        f32x4 cr = C4[i16 * 9 + k4];
        a0 += dotv(cr, P4[j16 * 9 + k4]);
        a1 += dotv(cr, P4[(j16 + 16) * 9 + k4]);
      }
      s.Aug[i16 * 52 + AD + j16] = a0;
      s.Aug[i16 * 52 + AD + j16 + 16] = a1;
    }
    __syncthreads();

    // P2: S = CP C^T + R -> Aug left (1 output/thread); r on 16 threads
    {
      float acc = s.Rs[i16 * AD + j16];
      #pragma unroll
      for (int k4 = 0; k4 < 8; ++k4)
        acc += dotv(Aug4[i16 * 13 + 4 + k4], C4[j16 * 9 + k4]);
      s.Aug[i16 * 52 + j16] = acc;
      if (l >= 240) {
        int ii = l - 240;
        float rr = s.af[ii];
        #pragma unroll
        for (int k4 = 0; k4 < 8; ++k4) rr -= dotv(C4[ii * 9 + k4], meanp4[k4]);
        s.r[ii] = rr;
      }
    }
    __syncthreads();

    // P3: wave 0 GJ -> K  |  waves 2-3 commit prefetched C (C dead after P2)
    if (l < 64) {
      const int lc = (l < 48) ? l : 47;
      float col[16];
      #pragma unroll
      for (int i = 0; i < AD; ++i) col[i] = s.Aug[i * 52 + lc];
      #pragma unroll
      for (int j = 0; j < AD; ++j) {
        float pd = __shfl(col[j], j);
        float pinv = 1.0f / pd;
        float oldj = col[j];
        #pragma unroll
        for (int i = 0; i < AD; ++i) {
          if (i == j) continue;
          float fi = __shfl(col[i], j);
          col[i] = fmaf(-(fi * pinv), oldj, col[i]);
        }
        col[j] = oldj * pinv;
      }
      if (l >= AD && l < AD + ZD) {
        int rr = l - AD;
        f32x4 v0 = {col[0], col[1], col[2], col[3]};
        f32x4 v1 = {col[4], col[5], col[6], col[7]};
        f32x4 v2 = {col[8], col[9], col[10], col[11]};
        f32x4 v3 = {col[12], col[13], col[14], col[15]};
        Kk4[rr * 5 + 0] = v0;
        Kk4[rr * 5 + 1] = v1;
        Kk4[rr * 5 + 2] = v2;
        Kk4[rr * 5 + 3] = v3;
      }
    } else if (pf && l >= 128) {
      int idx = l - 128;
      C4[(idx >> 3) * 9 + (idx & 7)] = pfC;
    }
    __syncthreads();

    // P4: cov_t = P - K@CP -> Mt, MtT (1 f32x4/thread, k4-outer)
    {
      f32x4 acc = {0.f, 0.f, 0.f, 0.f};
      #pragma unroll
      for (int k4 = 0; k4 < 4; ++k4) {
        f32x4 kv = Kk4[i32 * 5 + k4];
        #pragma unroll
        for (int kk = 0; kk < 4; ++kk) {
          f32x4 cpk = Aug4[(4 * k4 + kk) * 13 + 4 + cq];
          acc += kv[kk] * cpk;
        }
      }
      f32x4 mv = P4[i32 * 9 + cq] - acc;
      Mt4[i32 * 9 + cq] = mv;
      #pragma unroll
      for (int jj = 0; jj < 4; ++jj) s.MtT[(4 * cq + jj) * 36 + i32] = mv[jj];
    }
    __syncthreads();

    // P5: Sy = 0.5(Mt+MtT) + covs out; mean_t on lanes<32
    {
      f32x4 sv = 0.5f * (Mt4[i32 * 9 + cq] + MtT4[i32 * 9 + cq]);
      Sy4[i32 * 9 + cq] = sv;
      st_nt4(&o_covs[tb * 1024 + i32 * 32 + cq * 4], sv);
      if (l < ZD) {
        float acc = s.meanp[l];
        #pragma unroll
        for (int m = 0; m < 4; ++m) acc += dotv(Kk4[l * 5 + m], r4[m]);
        s.meant[l] = acc;
        st_nt(&o_means[tb * ZD + l], acc);
      }
    }
    __syncthreads();

    // P6: ACt = An @ Sy (Sy symmetric -> row dots; 1 f32x4/thread)
    {
      float c0 = 0.f, c1 = 0.f, c2 = 0.f, c3 = 0.f;
      #pragma unroll
      for (int k4 = 0; k4 < 8; ++k4) {
        f32x4 an = An4[i32 * 9 + k4];
        c0 += dotv(an, Sy4[(4 * cq + 0) * 9 + k4]);
        c1 += dotv(an, Sy4[(4 * cq + 1) * 9 + k4]);
        c2 += dotv(an, Sy4[(4 * cq + 2) * 9 + k4]);
        c3 += dotv(an, Sy4[(4 * cq + 3) * 9 + k4]);
      }
      f32x4 v = {c0, c1, c2, c3};
      ACt4[i32 * 9 + cq] = v;
    }
    __syncthreads();

    // P7: M2 = ACt @ An^T -> Mt/MtT; meanp' = An @ mean_t on lanes<32
    {
      if (l < ZD) {
        float acc = 0.f;
        #pragma unroll
        for (int k4 = 0; k4 < 8; ++k4) acc += dotv(An4[l * 9 + k4], meant4[k4]);
        s.meanp[l] = acc;
        st_nt(&o_nmean[tb * ZD + l], acc);
      }
      float c0 = 0.f, c1 = 0.f, c2 = 0.f, c3 = 0.f;
      #pragma unroll
      for (int k4 = 0; k4 < 8; ++k4) {
        f32x4 ac = ACt4[i32 * 9 + k4];
        c0 += dotv(ac, An4[(4 * cq + 0) * 9 + k4]);
        c1 += dotv(ac, An4[(4 * cq + 1) * 9 + k4]);
        c2 += dotv(ac, An4[(4 * cq + 2) * 9 + k4]);
        c3 += dotv(ac, An4[(4 * cq + 3) * 9 + k4]);
      }
      f32x4 mv = {c0, c1, c2, c3};
      Mt4[i32 * 9 + cq] = mv;
      #pragma unroll
      for (int jj = 0; jj < 4; ++jj) s.MtT[(4 * cq + jj) * 36 + i32] = mv[jj];
    }
    __syncthreads();

    // P8: P' = 0.5(M2+M2^T) + Q -> P + ncovs out
    {
      f32x4 pv = 0.5f * (Mt4[i32 * 9 + cq] + MtT4[i32 * 9 + cq]) + Q4[i32 * 9 + cq];
      P4[i32 * 9 + cq] = pv;
      st_nt4(&o_ncovs[tb * 1024 + i32 * 32 + cq * 4], pv);
    }
    __syncthreads();

    // P9: commit prefetched An + a
    if (pf) {
      An4[(l >> 3) * 9 + (l & 7)] = pfA;
      if (l < 4) af4[l] = pfa;
    }
    __syncthreads();
  }
}

extern "C" void kernel_launch(void* const* d_in, const int* in_sizes, int n_in,
                              void* d_out, int out_size, void* d_ws, size_t ws_size,
                              hipStream_t stream) {
  const float* as_ = (const float*)d_in[0];
  const float* AK = (const float*)d_in[1];
  const float* CK = (const float*)d_in[2];
  const float* QL = (const float*)d_in[3];
  const float* RL = (const float*)d_in[4];
  const float* initm = (const float*)d_in[5];
  const float* initc = (const float*)d_in[6];
  const float* Wih0 = (const float*)d_in[7];
  const float* Whh0 = (const float*)d_in[8];
  const float* bih0 = (const float*)d_in[9];
  const float* bhh0 = (const float*)d_in[10];
  const float* Wih1 = (const float*)d_in[11];
  const float* Whh1 = (const float*)d_in[12];
  const float* bih1 = (const float*)d_in[13];
  const float* bhh1 = (const float*)d_in[14];
  const float* Wout = (const float*)d_in[15];
  const float* bout = (const float*)d_in[16];
  float* ws = (float*)d_ws;
  float* out = (float*)d_out;

  ssm_prep_kernel<<<16, 256, 0, stream>>>(Wih0, Whh0, Wih1, Whh1, bih0, bhh0, bih1, bhh1,
                                          QL, RL, ws);
  ssm_lstm_kernel<<<B_SZ, NTHR, 0, stream>>>(as_, AK, CK, Wout, bout, ws, out);
  ssm_kalman_kernel<<<B_SZ, 256, 0, stream>>>(as_, initm, initc, ws, out);
}

// Round 21
// 1584.909 us; speedup vs baseline: 3.6380x; 1.0024x over previous
//
#include <hip/hip_runtime.h>
#include <hip/hip_fp16.h>
#include <math.h>

#define T_STEPS 128
#define B_SZ 256
#define AD 16
#define ZD 32
#define KM 8
#define HID 128
#define G4H 512
#define NTHR 512

// ws layout (4-byte word offsets)
#define WS_WQ   0
#define WS_WI0  98304
#define WS_BS0  102400
#define WS_BS1  102912
#define WS_Q    103424
#define WS_R    104448

typedef float f32x4 __attribute__((ext_vector_type(4)));

__device__ __forceinline__ unsigned pk16(float lo, float hi) {
  unsigned a = __half_as_ushort(__float2half_rn(lo));
  unsigned b = __half_as_ushort(__float2half_rn(hi));
  return a | (b << 16);
}

__global__ void ssm_prep_kernel(const float* __restrict__ Wih0, const float* __restrict__ Whh0,
                                const float* __restrict__ Wih1, const float* __restrict__ Whh1,
                                const float* __restrict__ bih0, const float* __restrict__ bhh0,
                                const float* __restrict__ bih1, const float* __restrict__ bhh1,
                                const float* __restrict__ QL, const float* __restrict__ RL,
                                float* __restrict__ ws) {
  unsigned* wsu = (unsigned*)ws;
  int tid = blockIdx.x * blockDim.x + threadIdx.x;
  int nt = gridDim.x * blockDim.x;
  for (int j = tid; j < G4H; j += nt) {
    for (int d4 = 0; d4 < 48; ++d4) {
      for (int m = 0; m < 4; ++m) {
        int dd = (d4 & 15) * 4 + m;
        const float* src = (d4 < 16) ? Whh0 : (d4 < 32) ? Wih1 : Whh1;
        wsu[WS_WQ + (d4 * 512 + j) * 4 + m] =
            pk16(src[j * 128 + 2 * dd], src[j * 128 + 2 * dd + 1]);
      }
    }
    for (int k = 0; k < 8; ++k)
      wsu[WS_WI0 + k * 512 + j] = pk16(Wih0[j * 16 + 2 * k], Wih0[j * 16 + 2 * k + 1]);
    ws[WS_BS0 + j] = bih0[j] + bhh0[j];
    ws[WS_BS1 + j] = bih1[j] + bhh1[j];
  }
  for (int e = tid; e < ZD * ZD; e += nt) {
    int i = e >> 5, j = e & 31;
    float s = 0.f;
    for (int k = 0; k < ZD; ++k) s += QL[i * ZD + k] * QL[j * ZD + k];
    if (i == j) s += 0.001f;
    ws[WS_Q + e] = s;
  }
  for (int e = tid; e < AD * AD; e += nt) {
    int i = e >> 4, j = e & 15;
    float s = 0.f;
    for (int k = 0; k < AD; ++k) s += RL[i * AD + k] * RL[j * AD + k];
    if (i == j) s += 0.001f;
    ws[WS_R + e] = s;
  }
}

__device__ __forceinline__ float sigm(float x) { return 1.0f / (1.0f + expf(-x)); }
__device__ __forceinline__ float dotv(f32x4 a, f32x4 b) {
  return a[0] * b[0] + a[1] * b[1] + a[2] * b[2] + a[3] * b[3];
}
__device__ __forceinline__ void st_nt(float* p, float v) { __builtin_nontemporal_store(v, p); }
__device__ __forceinline__ void st_nt4(float* p, f32x4 v) {
  __builtin_nontemporal_store(v, (f32x4*)p);
}

__device__ __forceinline__ float dot2f(unsigned a, unsigned b, float c) {
#if __has_builtin(__builtin_amdgcn_fdot2)
  typedef _Float16 h2 __attribute__((ext_vector_type(2)));
  union U { unsigned u; h2 h; };
  U ua, ub; ua.u = a; ub.u = b;
  return __builtin_amdgcn_fdot2(ua.h, ub.h, c, false);
#else
  union U { unsigned u; _Float16 h[2]; };
  U ua, ub; ua.u = a; ub.u = b;
  return c + (float)ua.h[0] * (float)ub.h[0] + (float)ua.h[1] * (float)ub.h[1];
#endif
}

// ============================ Kernel 1: LSTM chain ============================
struct alignas(16) LS {
  unsigned ap[8];
  unsigned h0p[64];
  unsigned h1p[64];
  float g[G4H];
  float lgp[16];
};

__global__ void __launch_bounds__(NTHR, 2) ssm_lstm_kernel(
    const float* __restrict__ as_, const float* __restrict__ AK, const float* __restrict__ CK,
    const float* __restrict__ Wout, const float* __restrict__ bout,
    const float* __restrict__ ws, float* __restrict__ out) {
  __shared__ LS s;
  const int tid = threadIdx.x;
  const int b = blockIdx.x;
  const unsigned* wsu = (const unsigned*)ws;
  const uint4* Wg = (const uint4*)(wsu + WS_WQ);
  const f32x4* AK4 = (const f32x4*)AK;
  const f32x4* CK4 = (const f32x4*)CK;

  float* o_As = out + (size_t)T_STEPS * B_SZ * ZD + (size_t)T_STEPS * B_SZ * ZD * ZD +
                (size_t)T_STEPS * B_SZ * ZD + (size_t)T_STEPS * B_SZ * ZD * ZD;
  float* o_Cs = o_As + (size_t)(T_STEPS + 1) * B_SZ * ZD * ZD;
  float* o_a = o_Cs + (size_t)(T_STEPS + 1) * B_SZ * AD * ZD;

  const uint4* h0p4 = (const uint4*)s.h0p;
  const uint4* h1p4 = (const uint4*)s.h1p;
  const uint4* ap4 = (const uint4*)s.ap;

  unsigned wi0r[8];
  #pragma unroll
  for (int k = 0; k < 8; ++k) wi0r[k] = wsu[WS_WI0 + k * 512 + tid];
  const float bs0r = ws[WS_BS0 + tid];
  const float bs1r = ws[WS_BS1 + tid];
  float woutr[8];
  #pragma unroll
  for (int gi = 0; gi < KM; ++gi) woutr[gi] = (tid < HID) ? Wout[gi * HID + tid] : 0.f;
  float boutr[8];
  #pragma unroll
  for (int k = 0; k < KM; ++k) boutr[k] = bout[k];

  float c0r = 0.f, c1r = 0.f;

  if (tid < 64) { s.h0p[tid] = 0u; s.h1p[tid] = 0u; }
  if (tid < AD) {
    float v = as_[(size_t)b * AD + tid];
    ((__half*)s.ap)[tid] = __float2half_rn(v);
    st_nt(&o_a[(size_t)b * AD + tid], v);
  }
  if (tid < 256) {
    f32x4 acc = {0.f, 0.f, 0.f, 0.f};
    #pragma unroll
    for (int k = 0; k < KM; ++k) acc += AK4[k * 256 + tid];
    st_nt4(&o_As[(size_t)b * 1024 + tid * 4], acc);
  } else if (tid < 384) {
    int idx = tid - 256;
    f32x4 acc = {0.f, 0.f, 0.f, 0.f};
    #pragma unroll
    for (int k = 0; k < KM; ++k) acc += CK4[k * 128 + idx];
    st_nt4(&o_Cs[(size_t)b * 512 + idx * 4], acc);
  }
  __syncthreads();

  for (int t = 0; t < T_STEPS; ++t) {
    const size_t tb2 = (size_t)(t + 1) * B_SZ + b;

    // A: L0 gates (stream W_hh0)
    {
      float acc = bs0r;
      #pragma unroll
      for (int k4 = 0; k4 < 2; ++k4) {
        uint4 av = ap4[k4];
        acc = dot2f(av.x, wi0r[k4 * 4 + 0], acc);
        acc = dot2f(av.y, wi0r[k4 * 4 + 1], acc);
        acc = dot2f(av.z, wi0r[k4 * 4 + 2], acc);
        acc = dot2f(av.w, wi0r[k4 * 4 + 3], acc);
      }
      #pragma unroll
      for (int d4 = 0; d4 < 16; ++d4) {
        uint4 w = Wg[d4 * 512 + tid];
        uint4 hv = h0p4[d4];
        acc = dot2f(hv.x, w.x, acc);
        acc = dot2f(hv.y, w.y, acc);
        acc = dot2f(hv.z, w.z, acc);
        acc = dot2f(hv.w, w.w, acc);
      }
      s.g[tid] = acc;
    }
    __syncthreads();

    // B: h0/c0
    if (tid < HID) {
      float ig = sigm(s.g[tid]);
      float fg = sigm(s.g[HID + tid]);
      float gg = tanhf(s.g[2 * HID + tid]);
      float og = sigm(s.g[3 * HID + tid]);
      c0r = fg * c0r + ig * gg;
      ((__half*)s.h0p)[tid] = __float2half_rn(og * tanhf(c0r));
    }
    __syncthreads();

    // C: L1 gates (stream W_ih1 + W_hh1)
    {
      float acc = bs1r;
      #pragma unroll
      for (int d4 = 0; d4 < 16; ++d4) {
        uint4 w = Wg[(16 + d4) * 512 + tid];
        uint4 hv = h0p4[d4];
        acc = dot2f(hv.x, w.x, acc);
        acc = dot2f(hv.y, w.y, acc);
        acc = dot2f(hv.z, w.z, acc);
        acc = dot2f(hv.w, w.w, acc);
      }
      #pragma unroll
      for (int d4 = 0; d4 < 16; ++d4) {
        uint4 w = Wg[(32 + d4) * 512 + tid];
        uint4 hv = h1p4[d4];
        acc = dot2f(hv.x, w.x, acc);
        acc = dot2f(hv.y, w.y, acc);
        acc = dot2f(hv.z, w.z, acc);
        acc = dot2f(hv.w, w.w, acc);
      }
      s.g[tid] = acc;
    }
    __syncthreads();

    // D: h1/c1 + logit partials
    if (tid < HID) {
      float ig = sigm(s.g[tid]);
      float fg = sigm(s.g[HID + tid]);
      float gg = tanhf(s.g[2 * HID + tid]);
      float og = sigm(s.g[3 * HID + tid]);
      c1r = fg * c1r + ig * gg;
      float h1u = og * tanhf(c1r);
      ((__half*)s.h1p)[tid] = __float2half_rn(h1u);
      int w2 = tid >> 6, lane = tid & 63;
      #pragma unroll
      for (int gi = 0; gi < KM; ++gi) {
        float p = woutr[gi] * h1u;
        #pragma unroll
        for (int m = 32; m >= 1; m >>= 1) p += __shfl_xor(p, m);
        if (lane == 0) s.lgp[w2 * KM + gi] = p;
      }
    }
    __syncthreads();

    // E: softmax + einsum outputs + a prefetch
    {
      float lg[KM];
      float mx = -1e30f;
      #pragma unroll
      for (int k = 0; k < KM; ++k) {
        lg[k] = s.lgp[k] + s.lgp[KM + k] + boutr[k];
        mx = fmaxf(mx, lg[k]);
      }
      float sum = 0.f;
      #pragma unroll
      for (int k = 0; k < KM; ++k) { lg[k] = expf(lg[k] - mx); sum += lg[k]; }
      float inv = 1.0f / sum;
      #pragma unroll
      for (int k = 0; k < KM; ++k) lg[k] *= inv;
      if (tid < 256) {
        f32x4 acc = {0.f, 0.f, 0.f, 0.f};
        #pragma unroll
        for (int k = 0; k < KM; ++k) acc += lg[k] * AK4[k * 256 + tid];
        st_nt4(&o_As[tb2 * 1024 + tid * 4], acc);
      } else if (tid < 384) {
        int idx = tid - 256;
        f32x4 acc = {0.f, 0.f, 0.f, 0.f};
        #pragma unroll
        for (int k = 0; k < KM; ++k) acc += lg[k] * CK4[k * 128 + idx];
        st_nt4(&o_Cs[tb2 * 512 + idx * 4], acc);
      } else if (tid >= 448 && tid < 448 + AD && t < T_STEPS - 1) {
        int i = tid - 448;
        float v = as_[tb2 * AD + i];
        ((__half*)s.ap)[i] = __float2half_rn(v);
        st_nt(&o_a[tb2 * AD + i], v);
      }
    }
    __syncthreads();
  }
}

// ===== Kernel 2: Kalman chain — 4 waves/batch, 8 barriers/step (P9 merged into P8:
// ===== An/af commits are safe there since P7 is the last An reader and is
// ===== barrier-separated; af next read is P2, two barriers away).
struct alignas(16) KS {
  float P[ZD * 36];
  float An[ZD * 36];
  float Mt[ZD * 36];
  float MtT[ZD * 36];
  float Sy[ZD * 36];
  float ACt[ZD * 36];
  float Qs[ZD * 36];
  float C[AD * 36];
  float Aug[AD * 52];    // [S(16) | CP(32)] per row
  float Kk[ZD * 20];
  float Rs[AD * AD];
  float meanp[ZD], meant[ZD], r[AD], af[AD];
};

__global__ void __launch_bounds__(256, 1) ssm_kalman_kernel(
    const float* __restrict__ as_, const float* __restrict__ initm,
    const float* __restrict__ initc, const float* __restrict__ ws,
    float* __restrict__ out) {
  __shared__ KS s;
  const int l = threadIdx.x;           // 0..255
  const int b = blockIdx.x;
  const int i32 = l & 31, cq = l >> 5; // 32-row f32x4 phases (2-way-max banks)
  const int i16 = l & 15, j16 = l >> 4;// 16-row phases

  float* o_means = out;
  float* o_covs = o_means + (size_t)T_STEPS * B_SZ * ZD;
  float* o_nmean = o_covs + (size_t)T_STEPS * B_SZ * ZD * ZD;
  float* o_ncovs = o_nmean + (size_t)T_STEPS * B_SZ * ZD;
  const float* o_As = o_ncovs + (size_t)T_STEPS * B_SZ * ZD * ZD;
  const float* o_Cs = o_As + (size_t)(T_STEPS + 1) * B_SZ * ZD * ZD;

  f32x4* P4 = (f32x4*)s.P;        // stride 9
  f32x4* An4 = (f32x4*)s.An;
  f32x4* Mt4 = (f32x4*)s.Mt;
  f32x4* MtT4 = (f32x4*)s.MtT;
  f32x4* Sy4 = (f32x4*)s.Sy;
  f32x4* ACt4 = (f32x4*)s.ACt;
  f32x4* Q4 = (f32x4*)s.Qs;
  f32x4* C4 = (f32x4*)s.C;
  f32x4* Aug4 = (f32x4*)s.Aug;    // stride 13; CP at +4
  f32x4* Kk4 = (f32x4*)s.Kk;      // stride 5
  f32x4* af4 = (f32x4*)s.af;
  const f32x4* r4 = (const f32x4*)s.r;
  const f32x4* meanp4 = (const f32x4*)s.meanp;
  const f32x4* meant4 = (const f32x4*)s.meant;

  // ---- init ----
  #pragma unroll
  for (int q = 0; q < 4; ++q) {
    int e = q * 256 + l;
    s.P[(e >> 5) * 36 + (e & 31)] = initc[e];
    s.Qs[(e >> 5) * 36 + (e & 31)] = ws[WS_Q + e];
  }
  s.Rs[l] = ws[WS_R + l];
  if (l < ZD) s.meanp[l] = initm[l];
  {
    const f32x4* gc = (const f32x4*)&o_Cs[(size_t)b * 512];
    if (l < 128) C4[(l >> 3) * 9 + (l & 7)] = gc[l];
    const f32x4* ga = (const f32x4*)&o_As[((size_t)B_SZ + b) * 1024];
    An4[(l >> 3) * 9 + (l & 7)] = ga[l];
    if (l < 4) af4[l] = ((const f32x4*)&as_[(size_t)b * AD])[l];
  }
  __syncthreads();

  for (int t = 0; t < T_STEPS; ++t) {
    const size_t tb = (size_t)t * B_SZ + b;
    const bool pf = (t < T_STEPS - 1);

    // P0: issue prefetch for step t+1 (registers; C committed in P3, An/a in P8)
    f32x4 pfC = {0, 0, 0, 0};
    f32x4 pfA = {0, 0, 0, 0};
    f32x4 pfa = {0, 0, 0, 0};
    if (pf) {
      if (l >= 128) pfC = ((const f32x4*)&o_Cs[(tb + B_SZ) * 512])[l - 128];
      pfA = ((const f32x4*)&o_As[(tb + 2 * B_SZ) * 1024])[l];
      if (l < 4) pfa = ((const f32x4*)&as_[(tb + B_SZ) * AD])[l];
    }

    // P1: CP = C @ P (P symmetric -> row dots) -> Aug right half (2 outputs/thread)
    {
      float a0 = 0.f, a1 = 0.f;
      #pragma unroll
      for (int k4 = 0; k4 < 8; ++k4) {
        f32x4 cr = C4[i16 * 9 + k4];
        a0 += dotv(cr, P4[j16 * 9 + k4]);
        a1 += dotv(cr, P4[(j16 + 16) * 9 + k4]);
      }
      s.Aug[i16 * 52 + AD + j16] = a0;
      s.Aug[i16 * 52 + AD + j16 + 16] = a1;
    }
    __syncthreads();

    // P2: S = CP C^T + R -> Aug left (1 output/thread); r on 16 threads
    {
      float acc = s.Rs[i16 * AD + j16];
      #pragma unroll
      for (int k4 = 0; k4 < 8; ++k4)
        acc += dotv(Aug4[i16 * 13 + 4 + k4], C4[j16 * 9 + k4]);
      s.Aug[i16 * 52 + j16] = acc;
      if (l >= 240) {
        int ii = l - 240;
        float rr = s.af[ii];
        #pragma unroll
        for (int k4 = 0; k4 < 8; ++k4) rr -= dotv(C4[ii * 9 + k4], meanp4[k4]);
        s.r[ii] = rr;
      }
    }
    __syncthreads();

    // P3: wave 0 GJ -> K  |  waves 2-3 commit prefetched C (C dead after P2)
    if (l < 64) {
      const int lc = (l < 48) ? l : 47;
      float col[16];
      #pragma unroll
      for (int i = 0; i < AD; ++i) col[i] = s.Aug[i * 52 + lc];
      #pragma unroll
      for (int j = 0; j < AD; ++j) {
        float pd = __shfl(col[j], j);
        float pinv = 1.0f / pd;
        float oldj = col[j];
        #pragma unroll
        for (int i = 0; i < AD; ++i) {
          if (i == j) continue;
          float fi = __shfl(col[i], j);
          col[i] = fmaf(-(fi * pinv), oldj, col[i]);
        }
        col[j] = oldj * pinv;
      }
      if (l >= AD && l < AD + ZD) {
        int rr = l - AD;
        f32x4 v0 = {col[0], col[1], col[2], col[3]};
        f32x4 v1 = {col[4], col[5], col[6], col[7]};
        f32x4 v2 = {col[8], col[9], col[10], col[11]};
        f32x4 v3 = {col[12], col[13], col[14], col[15]};
        Kk4[rr * 5 + 0] = v0;
        Kk4[rr * 5 + 1] = v1;
        Kk4[rr * 5 + 2] = v2;
        Kk4[rr * 5 + 3] = v3;
      }
    } else if (pf && l >= 128) {
      int idx = l - 128;
      C4[(idx >> 3) * 9 + (idx & 7)] = pfC;
    }
    __syncthreads();

    // P4: cov_t = P - K@CP -> Mt, MtT (1 f32x4/thread, k4-outer)
    {
      f32x4 acc = {0.f, 0.f, 0.f, 0.f};
      #pragma unroll
      for (int k4 = 0; k4 < 4; ++k4) {
        f32x4 kv = Kk4[i32 * 5 + k4];
        #pragma unroll
        for (int kk = 0; kk < 4; ++kk) {
          f32x4 cpk = Aug4[(4 * k4 + kk) * 13 + 4 + cq];
          acc += kv[kk] * cpk;
        }
      }
      f32x4 mv = P4[i32 * 9 + cq] - acc;
      Mt4[i32 * 9 + cq] = mv;
      #pragma unroll
      for (int jj = 0; jj < 4; ++jj) s.MtT[(4 * cq + jj) * 36 + i32] = mv[jj];
    }
    __syncthreads();

    // P5: Sy = 0.5(Mt+MtT) + covs out; mean_t on lanes<32
    {
      f32x4 sv = 0.5f * (Mt4[i32 * 9 + cq] + MtT4[i32 * 9 + cq]);
      Sy4[i32 * 9 + cq] = sv;
      st_nt4(&o_covs[tb * 1024 + i32 * 32 + cq * 4], sv);
      if (l < ZD) {
        float acc = s.meanp[l];
        #pragma unroll
        for (int m = 0; m < 4; ++m) acc += dotv(Kk4[l * 5 + m], r4[m]);
        s.meant[l] = acc;
        st_nt(&o_means[tb * ZD + l], acc);
      }
    }
    __syncthreads();

    // P6: ACt = An @ Sy (Sy symmetric -> row dots; 1 f32x4/thread)
    {
      float c0 = 0.f, c1 = 0.f, c2 = 0.f, c3 = 0.f;
      #pragma unroll
      for (int k4 = 0; k4 < 8; ++k4) {
        f32x4 an = An4[i32 * 9 + k4];
        c0 += dotv(an, Sy4[(4 * cq + 0) * 9 + k4]);
        c1 += dotv(an, Sy4[(4 * cq + 1) * 9 + k4]);
        c2 += dotv(an, Sy4[(4 * cq + 2) * 9 + k4]);
        c3 += dotv(an, Sy4[(4 * cq + 3) * 9 + k4]);
      }
      f32x4 v = {c0, c1, c2, c3};
      ACt4[i32 * 9 + cq] = v;
    }
    __syncthreads();

    // P7: M2 = ACt @ An^T -> Mt/MtT; meanp' = An @ mean_t on lanes<32 (last An read)
    {
      if (l < ZD) {
        float acc = 0.f;
        #pragma unroll
        for (int k4 = 0; k4 < 8; ++k4) acc += dotv(An4[l * 9 + k4], meant4[k4]);
        s.meanp[l] = acc;
        st_nt(&o_nmean[tb * ZD + l], acc);
      }
      float c0 = 0.f, c1 = 0.f, c2 = 0.f, c3 = 0.f;
      #pragma unroll
      for (int k4 = 0; k4 < 8; ++k4) {
        f32x4 ac = ACt4[i32 * 9 + k4];
        c0 += dotv(ac, An4[(4 * cq + 0) * 9 + k4]);
        c1 += dotv(ac, An4[(4 * cq + 1) * 9 + k4]);
        c2 += dotv(ac, An4[(4 * cq + 2) * 9 + k4]);
        c3 += dotv(ac, An4[(4 * cq + 3) * 9 + k4]);
      }
      f32x4 mv = {c0, c1, c2, c3};
      Mt4[i32 * 9 + cq] = mv;
      #pragma unroll
      for (int jj = 0; jj < 4; ++jj) s.MtT[(4 * cq + jj) * 36 + i32] = mv[jj];
    }
    __syncthreads();

    // P8: P' = 0.5(M2+M2^T) + Q -> P + ncovs out; commit prefetched An/a
    // (P9 merged: An dead since P7 barrier, af next read is P2 — both safe here)
    {
      f32x4 pv = 0.5f * (Mt4[i32 * 9 + cq] + MtT4[i32 * 9 + cq]) + Q4[i32 * 9 + cq];
      P4[i32 * 9 + cq] = pv;
      st_nt4(&o_ncovs[tb * 1024 + i32 * 32 + cq * 4], pv);
      if (pf) {
        An4[(l >> 3) * 9 + (l & 7)] = pfA;
        if (l < 4) af4[l] = pfa;
      }
    }
    __syncthreads();
  }
}

extern "C" void kernel_launch(void* const* d_in, const int* in_sizes, int n_in,
                              void* d_out, int out_size, void* d_ws, size_t ws_size,
                              hipStream_t stream) {
  const float* as_ = (const float*)d_in[0];
  const float* AK = (const float*)d_in[1];
  const float* CK = (const float*)d_in[2];
  const float* QL = (const float*)d_in[3];
  const float* RL = (const float*)d_in[4];
  const float* initm = (const float*)d_in[5];
  const float* initc = (const float*)d_in[6];
  const float* Wih0 = (const float*)d_in[7];
  const float* Whh0 = (const float*)d_in[8];
  const float* bih0 = (const float*)d_in[9];
  const float* bhh0 = (const float*)d_in[10];
  const float* Wih1 = (const float*)d_in[11];
  const float* Whh1 = (const float*)d_in[12];
  const float* bih1 = (const float*)d_in[13];
  const float* bhh1 = (const float*)d_in[14];
  const float* Wout = (const float*)d_in[15];
  const float* bout = (const float*)d_in[16];
  float* ws = (float*)d_ws;
  float* out = (float*)d_out;

  ssm_prep_kernel<<<16, 256, 0, stream>>>(Wih0, Whh0, Wih1, Whh1, bih0, bhh0, bih1, bhh1,
                                          QL, RL, ws);
  ssm_lstm_kernel<<<B_SZ, NTHR, 0, stream>>>(as_, AK, CK, Wout, bout, ws, out);
  ssm_kalman_kernel<<<B_SZ, 256, 0, stream>>>(as_, initm, initc, ws, out);
}